// Round 6
// baseline (881.057 us; speedup 1.0000x reference)
//
#include <hip/hip_runtime.h>
#include <hip/hip_bf16.h>

#define DEV __device__ __forceinline__

namespace {

constexpr int cB = 2, cT = 8, cH = 32, cW = 32, cC = 192;
constexpr int cDI = 384, cN = 16, cK = 4, cDTR = 12, cLT = 77, cHID = 768;
constexpr int cL  = cT * cH * cW;      // 8192
constexpr int cBL = cB * cL;           // 16384
constexpr int SEG = 128, SEGLEN = cL / SEG;   // 128 segments x 64 steps
constexpr int XROW = cDTR + 2 * cN;    // 44 live cols
constexpr int XSTR = 48;               // padded row stride (float4-aligned)

typedef __attribute__((ext_vector_type(8))) short bf16x8;
typedef __attribute__((ext_vector_type(4))) float f32x4;
typedef __attribute__((ext_vector_type(2))) float f32x2;
typedef __attribute__((ext_vector_type(4))) short short4v;

// ---------- scalar helpers ----------
DEV float bfu2f(unsigned short u) { return __uint_as_float(((unsigned)u) << 16); }
DEV float ldsel(const void* p, size_t i, int f32) {
  return f32 ? ((const float*)p)[i] : bfu2f(((const unsigned short*)p)[i]);
}
template <int F32>
DEV float4 ld4(const void* p, size_t e) {   // e: element index, multiple of 4
  if (F32) return *(const float4*)((const float*)p + e);
  ushort4 u = *(const ushort4*)((const unsigned short*)p + e);
  return make_float4(bfu2f(u.x), bfu2f(u.y), bfu2f(u.z), bfu2f(u.w));
}
DEV short f2bf(float f) {   // RNE float->bf16 bits
  unsigned u = __float_as_uint(f);
  u += 0x7fffu + ((u >> 16) & 1u);
  return (short)(u >> 16);
}
DEV float siluf(float x) { return x / (1.f + __expf(-x)); }
DEV float softplusf(float x) { return (x > 20.f) ? x : __logf(1.f + __expf(x)); }
DEV float gelut(float x) {            // tanh-approx gelu (JAX default)
  float u = 0.7978845608028654f * (x + 0.044715f * x * x * x);
  float e = __expf(2.f * u);
  float th = 1.f - 2.f / (e + 1.f);
  return 0.5f * x * (1.f + th);
}

// two adjacent-channel fp32 atomic adds (gfx950 has NO packed fp32 atomic;
// global_atomic_pk_add_* exists only for f16/bf16 — round-5 compile fail)
DEV void pk_atomic_add(float* p, float a, float b) {
  atomicAdd(p, a);
  atomicAdd(p + 1, b);
}

// power tree: pw[n] = a1^(n+1), depth 4
DEV void pow16(float a1, float (&pw)[cN]) {
  float a2 = a1*a1, a3 = a2*a1, a4 = a2*a2;
  float a5 = a4*a1, a6 = a4*a2, a7 = a4*a3, a8 = a4*a4;
  pw[0]=a1; pw[1]=a2; pw[2]=a3; pw[3]=a4; pw[4]=a5; pw[5]=a6; pw[6]=a7; pw[7]=a8;
  pw[8]=a8*a1; pw[9]=a8*a2; pw[10]=a8*a3; pw[11]=a8*a4;
  pw[12]=a8*a5; pw[13]=a8*a6; pw[14]=a8*a7; pw[15]=a8*a8;
}

template <int BS>
DEV void blkreduce2(float& a, float& b) {
  __shared__ float ra[BS], rb[BS];
  int t = threadIdx.x;
  ra[t] = a; rb[t] = b; __syncthreads();
#pragma unroll
  for (int s = BS / 2; s > 0; s >>= 1) {
    if (t < s) { ra[t] += ra[t + s]; rb[t] += rb[t + s]; }
    __syncthreads();
  }
  a = ra[0]; b = rb[0];
  __syncthreads();
}

// ---------- dtype detector (validated round 3: inputs are fp32) ----------
__global__ void __launch_bounds__(256) detect_kernel(
    const unsigned short* __restrict__ xa, const unsigned short* __restrict__ wp,
    int* __restrict__ flg) {
  __shared__ int cnt[2];
  if (threadIdx.x < 2) cnt[threadIdx.x] = 0;
  __syncthreads();
  int l0 = 0, l1 = 0;
  for (int i = threadIdx.x; i < 1024; i += 256) {
    float v = bfu2f(xa[2 * i]); float a = fabsf(v);
    if (v == 0.f || (a > 1e-8f && a < 1e4f)) l0++;
    float u = bfu2f(wp[2 * i]); float bq = fabsf(u);
    if (u == 0.f || (bq > 1e-8f && bq < 1e4f)) l1++;
  }
  atomicAdd(&cnt[0], l0); atomicAdd(&cnt[1], l1);
  __syncthreads();
  if (threadIdx.x == 0) {
    flg[0] = (cnt[0] < 614) ? 1 : 0;
    flg[1] = (cnt[1] < 614) ? 1 : 0;
    flg[2] = 1;
  }
}

// ---------- zero-fill ----------
__global__ void __launch_bounds__(256) zero4_kernel(float4* __restrict__ p, int n4) {
  int i = blockIdx.x * 256 + threadIdx.x;
  if (i < n4) p[i] = make_float4(0.f, 0.f, 0.f, 0.f);
}

// ---------- conv weight prep: transpose [Ch][27] -> [27][Ch] fp32, decode biases ----------
__global__ void __launch_bounds__(256) prep_kernel(
    const void* __restrict__ cvw, const void* __restrict__ cvb,
    const void* __restrict__ c1w, const void* __restrict__ c1b,
    const void* __restrict__ c2w, const void* __restrict__ c2b,
    const int* __restrict__ flg,
    float* __restrict__ wcv, float* __restrict__ bcv,
    float* __restrict__ w1, float* __restrict__ b1,
    float* __restrict__ w2, float* __restrict__ b2) {
  int pf = flg[1];
  int i = blockIdx.x * 256 + threadIdx.x;
  int r = i;
  if (r < 27 * cDI) { int j = r / cDI, d = r % cDI; wcv[r] = ldsel(cvw, (size_t)d * 27 + j, pf); return; }
  r -= 27 * cDI;
  if (r < cDI) { bcv[r] = ldsel(cvb, r, pf); return; }
  r -= cDI;
  if (r < 27 * cC) { int j = r / cC, c = r % cC; w1[r] = ldsel(c1w, (size_t)c * 27 + j, pf); return; }
  r -= 27 * cC;
  if (r < cC) { b1[r] = ldsel(c1b, r, pf); return; }
  r -= cC;
  if (r < 27 * cC) { int j = r / cC, c = r % cC; w2[r] = ldsel(c2w, (size_t)c * 27 + j, pf); return; }
  r -= 27 * cC;
  if (r < cC) { b2[r] = ldsel(c2b, r, pf); return; }
}

// ---------- CPE (depthwise 3x3x3 + residual), 4-channel vectorized ----------
template <int F32>
DEV void cpe_body(const void* __restrict__ xin, const float* __restrict__ wT,
                  const float* __restrict__ bs, int idx, float* __restrict__ out) {
  int c = (idx % (cC / 4)) * 4; int bv = idx / (cC / 4);
  int v = bv & (cL - 1); int b = bv >> 13;
  int t = v >> 10, q = v & 1023, h = q >> 5, w = q & 31;
  float4 acc = *(const float4*)(bs + c);
#pragma unroll
  for (int dz = 0; dz < 3; ++dz) {
    int tt = t + dz - 1; if ((unsigned)tt >= (unsigned)cT) continue;
#pragma unroll
    for (int dy = 0; dy < 3; ++dy) {
      int hh = h + dy - 1; if ((unsigned)hh >= (unsigned)cH) continue;
#pragma unroll
      for (int dx = 0; dx < 3; ++dx) {
        int ww = w + dx - 1; if ((unsigned)ww >= (unsigned)cW) continue;
        int vv = (tt << 10) + (hh << 5) + ww;
        float4 wv = *(const float4*)(wT + (dz * 9 + dy * 3 + dx) * cC + c);
        float4 xv = ld4<F32>(xin, ((size_t)b * cL + vv) * cC + c);
        acc.x += wv.x * xv.x; acc.y += wv.y * xv.y;
        acc.z += wv.z * xv.z; acc.w += wv.w * xv.w;
      }
    }
  }
  float4 x0 = ld4<F32>(xin, (size_t)bv * cC + c);
  float4 o = make_float4(x0.x + acc.x, x0.y + acc.y, x0.z + acc.z, x0.w + acc.w);
  *(float4*)(out + (size_t)bv * cC + c) = o;
}

__global__ void __launch_bounds__(256) cpe_kernel(
    const void* __restrict__ xin, const float* __restrict__ wT,
    const float* __restrict__ bs, const int* __restrict__ flg, int afidx,
    float* __restrict__ out) {
  int idx = blockIdx.x * 256 + threadIdx.x;
  if (idx >= cBL * cC / 4) return;
  if (flg[afidx]) cpe_body<1>(xin, wT, bs, idx, out);
  else            cpe_body<0>(xin, wT, bs, idx, out);
}

// ---------- depthwise conv on DI + SiLU, 4-channel vectorized ----------
__global__ void __launch_bounds__(256) dwconv_silu_kernel(
    const float* __restrict__ xin, const float* __restrict__ wT,
    const float* __restrict__ bs, float* __restrict__ out) {
  int idx = blockIdx.x * 256 + threadIdx.x;
  if (idx >= cBL * cDI / 4) return;
  int d = (idx % (cDI / 4)) * 4; int bv = idx / (cDI / 4);
  int v = bv & (cL - 1); int b = bv >> 13;
  int t = v >> 10, q = v & 1023, h = q >> 5, w = q & 31;
  float4 acc = *(const float4*)(bs + d);
#pragma unroll
  for (int dz = 0; dz < 3; ++dz) {
    int tt = t + dz - 1; if ((unsigned)tt >= (unsigned)cT) continue;
#pragma unroll
    for (int dy = 0; dy < 3; ++dy) {
      int hh = h + dy - 1; if ((unsigned)hh >= (unsigned)cH) continue;
#pragma unroll
      for (int dx = 0; dx < 3; ++dx) {
        int ww = w + dx - 1; if ((unsigned)ww >= (unsigned)cW) continue;
        int vv = (tt << 10) + (hh << 5) + ww;
        float4 wv = *(const float4*)(wT + (dz * 9 + dy * 3 + dx) * cDI + d);
        float4 xv = *(const float4*)(xin + ((size_t)b * cL + vv) * cDI + d);
        acc.x += wv.x * xv.x; acc.y += wv.y * xv.y;
        acc.z += wv.z * xv.z; acc.w += wv.w * xv.w;
      }
    }
  }
  float4 o = make_float4(siluf(acc.x), siluf(acc.y), siluf(acc.z), siluf(acc.w));
  *(float4*)(out + (size_t)bv * cDI + d) = o;
}

// ---------- row LayerNorm ----------
__global__ void __launch_bounds__(256) ln_kernel(
    const float* __restrict__ in, const void* __restrict__ g,
    const void* __restrict__ bb, const int* __restrict__ flg,
    float* __restrict__ out, int D) {
  int pf = flg[1];
  int row = blockIdx.x;
  const float* x = in + (size_t)row * D;
  float s1 = 0.f, s2 = 0.f;
  for (int i = threadIdx.x; i < D; i += 256) { float v = x[i]; s1 += v; s2 += v * v; }
  blkreduce2<256>(s1, s2);
  float mean = s1 / D;
  float var = s2 / D - mean * mean;
  float rstd = rsqrtf(var + 1e-6f);
  float* o = out + (size_t)row * D;
  for (int i = threadIdx.x; i < D; i += 256)
    o[i] = (x[i] - mean) * rstd * ldsel(g, i, pf) + ldsel(bb, i, pf);
}

// ---------- text conditioning ----------
__global__ void __launch_bounds__(384) text_cond_kernel(
    const void* __restrict__ text, const void* __restrict__ tw,
    const void* __restrict__ tb, const int* __restrict__ flg,
    float* __restrict__ cond) {
  int af = flg[0], pf = flg[1];
  __shared__ float mean[cC];
  int b = blockIdx.x;
  for (int c = threadIdx.x; c < cC; c += 384) {
    float s = 0.f;
    for (int t = 0; t < cLT; ++t) s += ldsel(text, ((size_t)b * cLT + t) * cC + c, af);
    mean[c] = s * (1.f / cLT);
  }
  __syncthreads();
  int di = threadIdx.x;
  float a = ldsel(tb, di, pf);
  for (int c = 0; c < cC; ++c) a += mean[c] * ldsel(tw, di * cC + c, pf);
  cond[b * cDI + di] = siluf(a);
}

// ---------- MFMA GEMM: out = epilogue(A[M,K]fp32 @ W[N,K]^T), bf16 compute ----------
// Tile 128x64, 256 threads = 4 waves (2x2 of 64x32), BK=32, 16x16x32 bf16 MFMA.
template <int MODE>
__global__ void __launch_bounds__(256) gemm_mfma_kernel(
    const float* __restrict__ A, const void* __restrict__ W,
    int N, int K, const void* __restrict__ bias, const int* __restrict__ flg,
    const float* __restrict__ extra, float* __restrict__ out,
    float* __restrict__ out2) {
  constexpr int BM = 128, BN = 64, BK = 32, PK = 40;
  __shared__ short As[BM * PK];
  __shared__ short Bs[BN * PK];
  int pf = flg[1];
  int tid = threadIdx.x;
  int m0 = blockIdx.y * BM, n0 = blockIdx.x * BN;
  int lane = tid & 63, wv = tid >> 6;
  int wm = (wv >> 1) * 64, wn = (wv & 1) * 32;
  int lr = lane & 15, quad = lane >> 4;
  f32x4 acc[4][2];
#pragma unroll
  for (int mi = 0; mi < 4; ++mi)
#pragma unroll
    for (int ni = 0; ni < 2; ++ni) { acc[mi][ni][0]=0.f; acc[mi][ni][1]=0.f; acc[mi][ni][2]=0.f; acc[mi][ni][3]=0.f; }
  int ar = tid >> 1, aks = (tid & 1) * 16;
  int wr = tid >> 2, wks = (tid & 3) * 8;
  for (int k0 = 0; k0 < K; k0 += BK) {
    {
      const float* ap = A + (size_t)(m0 + ar) * K + k0 + aks;
      short* da = &As[ar * PK + aks];
#pragma unroll
      for (int i = 0; i < 4; ++i) {
        float4 v = ((const float4*)ap)[i];
        short4v h; h.x = f2bf(v.x); h.y = f2bf(v.y); h.z = f2bf(v.z); h.w = f2bf(v.w);
        *(short4v*)(da + i * 4) = h;
      }
    }
    {
      int nr = n0 + wr;
      short hb[8];
      if (nr < N) {
        size_t wi = (size_t)nr * K + k0 + wks;
        if (pf) {
#pragma unroll
          for (int i = 0; i < 8; ++i) hb[i] = f2bf(((const float*)W)[wi + i]);
        } else {
#pragma unroll
          for (int i = 0; i < 8; ++i) hb[i] = (short)((const unsigned short*)W)[wi + i];
        }
      } else {
#pragma unroll
        for (int i = 0; i < 8; ++i) hb[i] = 0;
      }
      short* db = &Bs[wr * PK + wks];
#pragma unroll
      for (int i = 0; i < 8; i += 4) {
        short4v h; h.x = hb[i]; h.y = hb[i+1]; h.z = hb[i+2]; h.w = hb[i+3];
        *(short4v*)(db + i) = h;
      }
    }
    __syncthreads();
    bf16x8 af[4], bfr[2];
#pragma unroll
    for (int mi = 0; mi < 4; ++mi)
      af[mi] = *(const bf16x8*)&As[(wm + mi * 16 + lr) * PK + quad * 8];
#pragma unroll
    for (int ni = 0; ni < 2; ++ni)
      bfr[ni] = *(const bf16x8*)&Bs[(wn + ni * 16 + lr) * PK + quad * 8];
#pragma unroll
    for (int mi = 0; mi < 4; ++mi)
#pragma unroll
      for (int ni = 0; ni < 2; ++ni)
        acc[mi][ni] = __builtin_amdgcn_mfma_f32_16x16x32_bf16(af[mi], bfr[ni], acc[mi][ni], 0, 0, 0);
    __syncthreads();
  }
#pragma unroll
  for (int mi = 0; mi < 4; ++mi) {
#pragma unroll
    for (int ni = 0; ni < 2; ++ni) {
#pragma unroll
      for (int r = 0; r < 4; ++r) {
        int m = m0 + wm + mi * 16 + quad * 4 + r;
        int n = n0 + wn + ni * 16 + lr;
        float v = acc[mi][ni][r];
        if (MODE == 0) {
          float bv = ldsel(bias, n, pf);
          int b = m >> 13;
          if (n < cDI) out[(size_t)m * cDI + n] = v + bv + extra[b * cDI + n];
          else         out2[(size_t)m * cDI + (n - cDI)] = v + bv;
        } else if (MODE == 1) {
          if (n < cK * XROW) {
            int k = n / XROW, c = n - k * XROW;
            int b = m >> 13, vv = m & (cL - 1);
            int t = vv >> 10, q = vv & 1023, h = q >> 5, w = q & 31;
            int l1 = (t << 10) + (w << 5) + h;
            int lk = (k == 0) ? vv : (k == 1) ? l1 : (k == 2) ? (cL - 1 - vv) : (cL - 1 - l1);
            out[((size_t)(b * cK + k) * cL + lk) * XSTR + c] = v;
          }
        } else if (MODE == 2) {
          out[(size_t)m * cC + n] = v + extra[(size_t)m * cC + n];
        } else if (MODE == 3) {
          out[(size_t)m * cHID + n] = gelut(v + ldsel(bias, n, pf));
        } else {
          out[(size_t)m * cC + n] = v + ldsel(bias, n, pf) + extra[(size_t)m * cC + n];
        }
      }
    }
  }
}

// voxel index for scan position l in direction k
DEV int scan_voxel(int k, int l) {
  if (k == 0) return l;
  if (k == 2) return cL - 1 - l;
  int ll = (k == 1) ? l : (cL - 1 - l);
  int t = ll >> 10, q = ll & 1023, w = q >> 5, h = q & 31;
  return (t << 10) + (h << 5) + w;
}

// ---------- scan pass 1 ----------
// 192 threads cover all 384 channels (2/thread): rows staged once per (b,k,s)
// (was 3x), dual independent recurrences give 2x ILP on shared LDS row reads,
// coalesced f32x2 u loads. Atomic op count unchanged vs r4-intent (no packed
// fp32 atomic on gfx950) -> this round is the A/B for the atomic-wall theory.
__global__ void __launch_bounds__(192, 3) scan1_kernel(
    const float* __restrict__ xc, const float* __restrict__ xdbl,
    const void* __restrict__ dtw, const void* __restrict__ dtbv,
    const void* __restrict__ alog, const void* __restrict__ dsv,
    const int* __restrict__ flg,
    float* __restrict__ ysm, unsigned short* __restrict__ hend,
    unsigned short* __restrict__ pend) {
  __shared__ float rows[SEGLEN * XSTR];   // 64 x 48 floats = 12 KB
  int pf = flg[1];
  int tid = threadIdx.x;
  int d0 = tid * 2;
  int bks = blockIdx.x;
  int s = bks & (SEG - 1); int bk = bks >> 7; int k = bk & 3; int b = bk >> 2;
  int l0 = s * SEGLEN;
  {
    const float4* src = (const float4*)(xdbl + ((size_t)bk * cL + l0) * XSTR);
    float4* dst = (float4*)rows;
#pragma unroll
    for (int i = 0; i < 4; ++i)   // 768 float4 / 192 threads
      dst[tid + i * 192] = src[tid + i * 192];
  }
  float wdtA[cDTR], wdtB[cDTR];
#pragma unroll
  for (int r = 0; r < cDTR; ++r) {
    wdtA[r] = ldsel(dtw, (size_t)(k * cDI + d0) * cDTR + r, pf);
    wdtB[r] = ldsel(dtw, (size_t)(k * cDI + d0 + 1) * cDTR + r, pf);
  }
  float dtbA = ldsel(dtbv, k * cDI + d0, pf);
  float dtbB = ldsel(dtbv, k * cDI + d0 + 1, pf);
  float acA[cN], acB[cN];
#pragma unroll
  for (int n = 0; n < cN; ++n) {
    acA[n] = -__expf(ldsel(alog, (size_t)(k * cDI + d0) * cN + n, pf)) * 1.4426950408889634f;
    acB[n] = -__expf(ldsel(alog, (size_t)(k * cDI + d0 + 1) * cN + n, pf)) * 1.4426950408889634f;
  }
  bool fast = true;
#pragma unroll
  for (int n = 1; n < cN; ++n) {
    fast = fast && (fabsf(acA[n] - (float)(n + 1) * acA[0]) <= 1e-3f * fabsf(acA[n]));
    fast = fast && (fabsf(acB[n] - (float)(n + 1) * acB[0]) <= 1e-3f * fabsf(acB[n]));
  }
  float DsA = ldsel(dsv, k * cDI + d0, pf);
  float DsB = ldsel(dsv, k * cDI + d0 + 1, pf);
  float hA[cN], hB[cN];
#pragma unroll
  for (int n = 0; n < cN; ++n) { hA[n] = 0.f; hB[n] = 0.f; }
  size_t so = ((size_t)bks * cDI + d0) * cN;   // channel A; channel B at so+cN
  const float* xcb = xc + (size_t)b * cL * cDI + d0;
  float* ysb = ysm + (size_t)b * cL * cDI + d0;
  __syncthreads();
  if (fast) {
    float ac0A = acA[0], ac0B = acB[0];
    float P1A = 1.f, P1B = 1.f;
    f32x2 uu = *(const f32x2*)(xcb + (size_t)scan_voxel(k, l0) * cDI);
    for (int st = 0; st < SEGLEN; ++st) {
      const float4* rp = (const float4*)(rows + st * XSTR);
      float4 q0 = rp[0], q1 = rp[1], q2 = rp[2];
      float sA0 = dtbA + q0.x*wdtA[0] + q0.z*wdtA[2] + q1.x*wdtA[4] + q1.z*wdtA[6] + q2.x*wdtA[8] + q2.z*wdtA[10];
      float sA1 = q0.y*wdtA[1] + q0.w*wdtA[3] + q1.y*wdtA[5] + q1.w*wdtA[7] + q2.y*wdtA[9] + q2.w*wdtA[11];
      float sB0 = dtbB + q0.x*wdtB[0] + q0.z*wdtB[2] + q1.x*wdtB[4] + q1.z*wdtB[6] + q2.x*wdtB[8] + q2.z*wdtB[10];
      float sB1 = q0.y*wdtB[1] + q0.w*wdtB[3] + q1.y*wdtB[5] + q1.w*wdtB[7] + q2.y*wdtB[9] + q2.w*wdtB[11];
      float dtA = softplusf(sA0 + sA1);
      float dtB = softplusf(sB0 + sB1);
      float a1A = exp2f(dtA * ac0A), a1B = exp2f(dtB * ac0B);
      int v = scan_voxel(k, l0 + st);
      int stn = (st + 1 < SEGLEN) ? st + 1 : SEGLEN - 1;
      // prefetch next u BEFORE the atomic so its vmcnt wait never drains one
      f32x2 uun = *(const f32x2*)(xcb + (size_t)scan_voxel(k, l0 + stn) * cDI);
      float pwA[cN], pwB[cN];
      pow16(a1A, pwA); pow16(a1B, pwB);
      float Bv[cN], Cv[cN];
      {
        float4 t3 = rp[3], t4 = rp[4], t5 = rp[5], t6 = rp[6];
        Bv[0]=t3.x; Bv[1]=t3.y; Bv[2]=t3.z; Bv[3]=t3.w;
        Bv[4]=t4.x; Bv[5]=t4.y; Bv[6]=t4.z; Bv[7]=t4.w;
        Bv[8]=t5.x; Bv[9]=t5.y; Bv[10]=t5.z; Bv[11]=t5.w;
        Bv[12]=t6.x; Bv[13]=t6.y; Bv[14]=t6.z; Bv[15]=t6.w;
        float4 t7 = rp[7], t8 = rp[8], t9 = rp[9], t10 = rp[10];
        Cv[0]=t7.x; Cv[1]=t7.y; Cv[2]=t7.z; Cv[3]=t7.w;
        Cv[4]=t8.x; Cv[5]=t8.y; Cv[6]=t8.z; Cv[7]=t8.w;
        Cv[8]=t9.x; Cv[9]=t9.y; Cv[10]=t9.z; Cv[11]=t9.w;
        Cv[12]=t10.x; Cv[13]=t10.y; Cv[14]=t10.z; Cv[15]=t10.w;
      }
      float dtuA = dtA * uu[0], dtuB = dtB * uu[1];
      P1A *= a1A; P1B *= a1B;
      float yA[4] = {DsA * uu[0], 0.f, 0.f, 0.f};
      float yB[4] = {DsB * uu[1], 0.f, 0.f, 0.f};
#pragma unroll
      for (int n = 0; n < cN; ++n) {
        hA[n] = hA[n] * pwA[n] + dtuA * Bv[n]; yA[n & 3] += hA[n] * Cv[n];
        hB[n] = hB[n] * pwB[n] + dtuB * Bv[n]; yB[n & 3] += hB[n] * Cv[n];
      }
      pk_atomic_add(ysb + (size_t)v * cDI,
                    (yA[0] + yA[1]) + (yA[2] + yA[3]),
                    (yB[0] + yB[1]) + (yB[2] + yB[3]));
      uu = uun;
    }
    float ppA = P1A, ppB = P1B;
#pragma unroll
    for (int n = 0; n < cN; ++n) {
      hend[so + n] = (unsigned short)f2bf(hA[n]);
      pend[so + n] = (unsigned short)f2bf(ppA); ppA *= P1A;
      hend[so + cN + n] = (unsigned short)f2bf(hB[n]);
      pend[so + cN + n] = (unsigned short)f2bf(ppB); ppB *= P1B;
    }
  } else {
    float PA[cN], PB[cN];
#pragma unroll
    for (int n = 0; n < cN; ++n) { PA[n] = 1.f; PB[n] = 1.f; }
    for (int st = 0; st < SEGLEN; ++st) {
      const float4* rp = (const float4*)(rows + st * XSTR);
      float4 q0 = rp[0], q1 = rp[1], q2 = rp[2];
      float sA0 = dtbA + q0.x*wdtA[0] + q0.z*wdtA[2] + q1.x*wdtA[4] + q1.z*wdtA[6] + q2.x*wdtA[8] + q2.z*wdtA[10];
      float sA1 = q0.y*wdtA[1] + q0.w*wdtA[3] + q1.y*wdtA[5] + q1.w*wdtA[7] + q2.y*wdtA[9] + q2.w*wdtA[11];
      float sB0 = dtbB + q0.x*wdtB[0] + q0.z*wdtB[2] + q1.x*wdtB[4] + q1.z*wdtB[6] + q2.x*wdtB[8] + q2.z*wdtB[10];
      float sB1 = q0.y*wdtB[1] + q0.w*wdtB[3] + q1.y*wdtB[5] + q1.w*wdtB[7] + q2.y*wdtB[9] + q2.w*wdtB[11];
      float dtA = softplusf(sA0 + sA1);
      float dtB = softplusf(sB0 + sB1);
      float Bv[cN], Cv[cN];
      {
        float4 t3 = rp[3], t4 = rp[4], t5 = rp[5], t6 = rp[6];
        Bv[0]=t3.x; Bv[1]=t3.y; Bv[2]=t3.z; Bv[3]=t3.w;
        Bv[4]=t4.x; Bv[5]=t4.y; Bv[6]=t4.z; Bv[7]=t4.w;
        Bv[8]=t5.x; Bv[9]=t5.y; Bv[10]=t5.z; Bv[11]=t5.w;
        Bv[12]=t6.x; Bv[13]=t6.y; Bv[14]=t6.z; Bv[15]=t6.w;
        float4 t7 = rp[7], t8 = rp[8], t9 = rp[9], t10 = rp[10];
        Cv[0]=t7.x; Cv[1]=t7.y; Cv[2]=t7.z; Cv[3]=t7.w;
        Cv[4]=t8.x; Cv[5]=t8.y; Cv[6]=t8.z; Cv[7]=t8.w;
        Cv[8]=t9.x; Cv[9]=t9.y; Cv[10]=t9.z; Cv[11]=t9.w;
        Cv[12]=t10.x; Cv[13]=t10.y; Cv[14]=t10.z; Cv[15]=t10.w;
      }
      int v = scan_voxel(k, l0 + st);
      f32x2 uu = *(const f32x2*)(xcb + (size_t)v * cDI);
      float dtuA = dtA * uu[0], dtuB = dtB * uu[1];
      float yA = DsA * uu[0], yB = DsB * uu[1];
#pragma unroll
      for (int n = 0; n < cN; ++n) {
        float aA = exp2f(dtA * acA[n]);
        hA[n] = hA[n] * aA + dtuA * Bv[n]; PA[n] *= aA; yA += hA[n] * Cv[n];
        float aB = exp2f(dtB * acB[n]);
        hB[n] = hB[n] * aB + dtuB * Bv[n]; PB[n] *= aB; yB += hB[n] * Cv[n];
      }
      pk_atomic_add(ysb + (size_t)v * cDI, yA, yB);
    }
#pragma unroll
    for (int n = 0; n < cN; ++n) {
      hend[so + n] = (unsigned short)f2bf(hA[n]);
      pend[so + n] = (unsigned short)f2bf(PA[n]);
      hend[so + cN + n] = (unsigned short)f2bf(hB[n]);
      pend[so + cN + n] = (unsigned short)f2bf(PB[n]);
    }
  }
}

// ---------- scan pass 2 (serial prefix over segments; fp32 recurrence, bf16 storage) ----------
__global__ void __launch_bounds__(256) scan2_kernel(
    unsigned short* __restrict__ hend, const unsigned short* __restrict__ pend) {
  int tid = blockIdx.x * 256 + threadIdx.x;
  int bk = tid / (cDI * cN); int r = tid - bk * (cDI * cN);
  float g = 0.f;
  for (int s = 0; s < SEG; ++s) {
    size_t o = ((size_t)(bk * SEG + s) * cDI * cN) + r;
    float he = bfu2f(hend[o]), pe = bfu2f(pend[o]);
    hend[o] = (unsigned short)f2bf(g);
    g = pe * g + he;
  }
}

// ---------- scan pass 3 ----------
__global__ void __launch_bounds__(192, 3) scan3_kernel(
    const float* __restrict__ xdbl,
    const void* __restrict__ dtw, const void* __restrict__ dtbv,
    const void* __restrict__ alog, const int* __restrict__ flg,
    const unsigned short* __restrict__ hin, float* __restrict__ ysm) {
  int bks = blockIdx.x;
  int s = bks & (SEG - 1);
  if (s == 0) return;
  __shared__ float rows[SEGLEN * XSTR];
  int pf = flg[1];
  int tid = threadIdx.x;
  int d0 = tid * 2;
  int bk = bks >> 7; int k = bk & 3; int b = bk >> 2;
  int l0 = s * SEGLEN;
  {
    const float4* src = (const float4*)(xdbl + ((size_t)bk * cL + l0) * XSTR);
    float4* dst = (float4*)rows;
#pragma unroll
    for (int i = 0; i < 4; ++i)
      dst[tid + i * 192] = src[tid + i * 192];
  }
  float wdtA[cDTR], wdtB[cDTR];
#pragma unroll
  for (int r = 0; r < cDTR; ++r) {
    wdtA[r] = ldsel(dtw, (size_t)(k * cDI + d0) * cDTR + r, pf);
    wdtB[r] = ldsel(dtw, (size_t)(k * cDI + d0 + 1) * cDTR + r, pf);
  }
  float dtbA = ldsel(dtbv, k * cDI + d0, pf);
  float dtbB = ldsel(dtbv, k * cDI + d0 + 1, pf);
  float acA[cN], acB[cN];
#pragma unroll
  for (int n = 0; n < cN; ++n) {
    acA[n] = -__expf(ldsel(alog, (size_t)(k * cDI + d0) * cN + n, pf)) * 1.4426950408889634f;
    acB[n] = -__expf(ldsel(alog, (size_t)(k * cDI + d0 + 1) * cN + n, pf)) * 1.4426950408889634f;
  }
  bool fast = true;
#pragma unroll
  for (int n = 1; n < cN; ++n) {
    fast = fast && (fabsf(acA[n] - (float)(n + 1) * acA[0]) <= 1e-3f * fabsf(acA[n]));
    fast = fast && (fabsf(acB[n] - (float)(n + 1) * acB[0]) <= 1e-3f * fabsf(acB[n]));
  }
  float gA[cN], gB[cN];
  size_t so = ((size_t)bks * cDI + d0) * cN;
#pragma unroll
  for (int n = 0; n < cN; ++n) {
    gA[n] = bfu2f(hin[so + n]);
    gB[n] = bfu2f(hin[so + cN + n]);
  }
  float* ysb = ysm + (size_t)b * cL * cDI + d0;
  __syncthreads();
  if (fast) {
    float ac0A = acA[0], ac0B = acB[0];
    for (int st = 0; st < SEGLEN; ++st) {
      const float4* rp = (const float4*)(rows + st * XSTR);
      float4 q0 = rp[0], q1 = rp[1], q2 = rp[2];
      float sA0 = dtbA + q0.x*wdtA[0] + q0.z*wdtA[2] + q1.x*wdtA[4] + q1.z*wdtA[6] + q2.x*wdtA[8] + q2.z*wdtA[10];
      float sA1 = q0.y*wdtA[1] + q0.w*wdtA[3] + q1.y*wdtA[5] + q1.w*wdtA[7] + q2.y*wdtA[9] + q2.w*wdtA[11];
      float sB0 = dtbB + q0.x*wdtB[0] + q0.z*wdtB[2] + q1.x*wdtB[4] + q1.z*wdtB[6] + q2.x*wdtB[8] + q2.z*wdtB[10];
      float sB1 = q0.y*wdtB[1] + q0.w*wdtB[3] + q1.y*wdtB[5] + q1.w*wdtB[7] + q2.y*wdtB[9] + q2.w*wdtB[11];
      float dtA = softplusf(sA0 + sA1);
      float dtB = softplusf(sB0 + sB1);
      float a1A = exp2f(dtA * ac0A), a1B = exp2f(dtB * ac0B);
      float pwA[cN], pwB[cN];
      pow16(a1A, pwA); pow16(a1B, pwB);
      float Cv[cN];
      {
        float4 t7 = rp[7], t8 = rp[8], t9 = rp[9], t10 = rp[10];
        Cv[0]=t7.x; Cv[1]=t7.y; Cv[2]=t7.z; Cv[3]=t7.w;
        Cv[4]=t8.x; Cv[5]=t8.y; Cv[6]=t8.z; Cv[7]=t8.w;
        Cv[8]=t9.x; Cv[9]=t9.y; Cv[10]=t9.z; Cv[11]=t9.w;
        Cv[12]=t10.x; Cv[13]=t10.y; Cv[14]=t10.z; Cv[15]=t10.w;
      }
      float yA[4] = {0.f, 0.f, 0.f, 0.f};
      float yB[4] = {0.f, 0.f, 0.f, 0.f};
#pragma unroll
      for (int n = 0; n < cN; ++n) {
        gA[n] *= pwA[n]; yA[n & 3] += gA[n] * Cv[n];
        gB[n] *= pwB[n]; yB[n & 3] += gB[n] * Cv[n];
      }
      int v = scan_voxel(k, l0 + st);
      pk_atomic_add(ysb + (size_t)v * cDI,
                    (yA[0] + yA[1]) + (yA[2] + yA[3]),
                    (yB[0] + yB[1]) + (yB[2] + yB[3]));
    }
  } else {
    for (int st = 0; st < SEGLEN; ++st) {
      const float4* rp = (const float4*)(rows + st * XSTR);
      float4 q0 = rp[0], q1 = rp[1], q2 = rp[2];
      float sA0 = dtbA + q0.x*wdtA[0] + q0.z*wdtA[2] + q1.x*wdtA[4] + q1.z*wdtA[6] + q2.x*wdtA[8] + q2.z*wdtA[10];
      float sA1 = q0.y*wdtA[1] + q0.w*wdtA[3] + q1.y*wdtA[5] + q1.w*wdtA[7] + q2.y*wdtA[9] + q2.w*wdtA[11];
      float sB0 = dtbB + q0.x*wdtB[0] + q0.z*wdtB[2] + q1.x*wdtB[4] + q1.z*wdtB[6] + q2.x*wdtB[8] + q2.z*wdtB[10];
      float sB1 = q0.y*wdtB[1] + q0.w*wdtB[3] + q1.y*wdtB[5] + q1.w*wdtB[7] + q2.y*wdtB[9] + q2.w*wdtB[11];
      float dtA = softplusf(sA0 + sA1);
      float dtB = softplusf(sB0 + sB1);
      float Cv[cN];
      {
        float4 t7 = rp[7], t8 = rp[8], t9 = rp[9], t10 = rp[10];
        Cv[0]=t7.x; Cv[1]=t7.y; Cv[2]=t7.z; Cv[3]=t7.w;
        Cv[4]=t8.x; Cv[5]=t8.y; Cv[6]=t8.z; Cv[7]=t8.w;
        Cv[8]=t9.x; Cv[9]=t9.y; Cv[10]=t9.z; Cv[11]=t9.w;
        Cv[12]=t10.x; Cv[13]=t10.y; Cv[14]=t10.z; Cv[15]=t10.w;
      }
      float yA = 0.f, yB = 0.f;
#pragma unroll
      for (int n = 0; n < cN; ++n) {
        float aA = exp2f(dtA * acA[n]); gA[n] *= aA; yA += gA[n] * Cv[n];
        float aB = exp2f(dtB * acB[n]); gB[n] *= aB; yB += gB[n] * Cv[n];
      }
      int v = scan_voxel(k, l0 + st);
      pk_atomic_add(ysb + (size_t)v * cDI, yA, yB);
    }
  }
}

// ---------- out_norm LN over merged ysm + silu(z) gate ----------
__global__ void __launch_bounds__(128) merge_kernel(
    const float* __restrict__ ysm, const float* __restrict__ z,
    const void* __restrict__ ong, const void* __restrict__ onb,
    const int* __restrict__ flg, float* __restrict__ yg) {
  int pf = flg[1];
  int bv = blockIdx.x;
  const float* yr = ysm + (size_t)bv * cDI;
  float vals[3]; float s1 = 0.f, s2 = 0.f;
#pragma unroll
  for (int i = 0; i < 3; ++i) {
    int d = threadIdx.x + i * 128;
    float x = yr[d];
    vals[i] = x; s1 += x; s2 += x * x;
  }
  blkreduce2<128>(s1, s2);
  float mean = s1 * (1.f / cDI);
  float var = s2 * (1.f / cDI) - mean * mean;
  float rstd = rsqrtf(var + 1e-6f);
  const float* zr = z + (size_t)bv * cDI;
  float* og = yg + (size_t)bv * cDI;
#pragma unroll
  for (int i = 0; i < 3; ++i) {
    int d = threadIdx.x + i * 128;
    float xn = (vals[i] - mean) * rstd * ldsel(ong, d, pf) + ldsel(onb, d, pf);
    og[d] = xn * siluf(zr[d]);
  }
}

}  // namespace

extern "C" void kernel_launch(void* const* d_in, const int* in_sizes, int n_in,
                              void* d_out, int out_size, void* d_ws, size_t ws_size,
                              hipStream_t stream) {
  (void)in_sizes; (void)n_in; (void)out_size; (void)ws_size;
  const void* x    = d_in[0];
  const void* text = d_in[1];
  const void* c1w  = d_in[2];
  const void* c1b  = d_in[3];
  const void* c2w  = d_in[4];
  const void* c2b  = d_in[5];
  const void* n1g  = d_in[6];
  const void* n1b  = d_in[7];
  const void* n2g  = d_in[8];
  const void* n2b  = d_in[9];
  const void* ipw  = d_in[10];
  const void* ipb  = d_in[11];
  const void* tpw  = d_in[12];
  const void* tpb  = d_in[13];
  const void* cvw  = d_in[14];
  const void* cvb  = d_in[15];
  const void* xpw  = d_in[16];
  const void* dtw  = d_in[17];
  const void* dtb  = d_in[18];
  const void* alog = d_in[19];
  const void* dsv  = d_in[20];
  const void* ong  = d_in[21];
  const void* onb  = d_in[22];
  const void* opw  = d_in[23];
  const void* f1w  = d_in[24];
  const void* f1b  = d_in[25];
  const void* f2w  = d_in[26];
  const void* f2b  = d_in[27];

  float* Wf = (float*)d_ws;

  // ---- slot arena (~125.9 MB); liveness as audited rounds 1-5 ----
  // SEG=128 checkpoints are bf16 (ushort): B*K*SEG*DI*N = 6.29M elems = 12.58 MB
  // each -> exactly fills a 3,145,728-float slot (oF for hend, oG for pend).
  constexpr size_t oC  = 0;                              // 6,291,456
  constexpr size_t oD  = 6291456;                        // 3,145,728
  constexpr size_t oG  = 9437184;                        // 3,145,728
  constexpr size_t oA  = 12582912;                       // 6,291,456
  constexpr size_t oB  = 18874368;                       // 6,291,456
  constexpr size_t oE  = 25165824;                       // 3,145,728
  constexpr size_t oF  = 28311552;                       // 3,145,728
  constexpr size_t oCO = 31457280;                       // 768 (cond)
  constexpr size_t oFL = 31458048;                       // 4 ints (flags)
  // conv prep area (fp32): transposed weights + biases
  constexpr size_t oWCV = 31458052;                      // 27*384 = 10368
  constexpr size_t oBCV = 31468420;                      // 384
  constexpr size_t oW1  = 31468804;                      // 27*192 = 5184
  constexpr size_t oB1  = 31473988;                      // 192
  constexpr size_t oW2  = 31474180;                      // 5184
  constexpr size_t oB2  = 31479364;                      // 192 -> end 31479556 (~125.9MB)
  float* xc   = Wf + oC;
  float* xdbl = Wf + oD;
  float* xn   = Wf + oG;
  unsigned short* pendp = (unsigned short*)(Wf + oG);    // bf16, after xn dead
  float* xi   = Wf + oA;
  float* ysm  = Wf + oA;
  float* x2   = Wf + oA;
  float* z    = Wf + oB;
  float* yg   = Wf + oB;
  float* x3   = Wf + oB;
  float* x1   = Wf + oE;
  unsigned short* hendp = (unsigned short*)(Wf + oF);    // bf16
  float* xn2  = Wf + oF;
  float* cond = Wf + oCO;
  float* hbuf = Wf + oC;
  int*   flg  = (int*)(Wf + oFL);
  float* wcv = Wf + oWCV; float* bcv = Wf + oBCV;
  float* w1t = Wf + oW1;  float* b1t = Wf + oB1;
  float* w2t = Wf + oW2;  float* b2t = Wf + oB2;

  const int cpeBlocks = (cBL * cC / 4) / 256;     // 3072
  const int dwBlocks  = (cBL * cDI / 4) / 256;    // 6144

  // 0. dtype detection + conv weight prep
  hipLaunchKernelGGL(detect_kernel, dim3(1), dim3(256), 0, stream,
                     (const unsigned short*)x, (const unsigned short*)ipw, flg);
  hipLaunchKernelGGL(prep_kernel, dim3(85), dim3(256), 0, stream,
                     cvw, cvb, c1w, c1b, c2w, c2b, flg, wcv, bcv, w1t, b1t, w2t, b2t);
  // 1. x1 = x + cpe1(x)
  hipLaunchKernelGGL(cpe_kernel, dim3(cpeBlocks), dim3(256), 0, stream,
                     x, w1t, b1t, flg, 0, x1);
  // 2. xn = LN1(x1)
  hipLaunchKernelGGL(ln_kernel, dim3(cBL), dim3(256), 0, stream, x1, n1g, n1b, flg, xn, cC);
  // 3. cond
  hipLaunchKernelGGL(text_cond_kernel, dim3(cB), dim3(384), 0, stream, text, tpw, tpb, flg, cond);
  // 4. in_proj (MFMA): xn -> xi (+cond), z
  hipLaunchKernelGGL((gemm_mfma_kernel<0>), dim3(2 * cDI / 64, cBL / 128), dim3(256), 0, stream,
                     xn, ipw, 2 * cDI, cC, ipb, flg, cond, xi, z);
  // 5. xc = silu(dwconv(xi))
  hipLaunchKernelGGL(dwconv_silu_kernel, dim3(dwBlocks), dim3(256), 0, stream,
                     xi, wcv, bcv, xc);
  // 6. zero ysm
  hipLaunchKernelGGL(zero4_kernel, dim3(cBL * cDI / 4 / 256), dim3(256), 0, stream,
                     (float4*)ysm, cBL * cDI / 4);
  // 7. x_proj (MFMA, scatter to padded scan rows)
  hipLaunchKernelGGL((gemm_mfma_kernel<1>), dim3((cK * XROW + 63) / 64, cBL / 128), dim3(256), 0, stream,
                     xc, xpw, cK * XROW, cDI, (const void*)nullptr, flg,
                     (const float*)nullptr, xdbl, (float*)nullptr);
  // 8-10. chunked selective scan (192-thread blocks, 2 channels/thread,
  //       shared staging, dual-recurrence ILP; scalar fp32 atomics)
  hipLaunchKernelGGL(scan1_kernel, dim3(cB * cK * SEG), dim3(192), 0, stream,
                     xc, xdbl, dtw, dtb, alog, dsv, flg, ysm, hendp, pendp);
  hipLaunchKernelGGL(scan2_kernel, dim3(cB * cK * cDI * cN / 256), dim3(256), 0, stream,
                     hendp, pendp);
  hipLaunchKernelGGL(scan3_kernel, dim3(cB * cK * SEG), dim3(192), 0, stream,
                     xdbl, dtw, dtb, alog, flg, hendp, ysm);
  // 11. out_norm + gate
  hipLaunchKernelGGL(merge_kernel, dim3(cBL), dim3(128), 0, stream, ysm, z, ong, onb, flg, yg);
  // 12. out_proj + residual(x1) -> x2 (MFMA)
  hipLaunchKernelGGL((gemm_mfma_kernel<2>), dim3(cC / 64, cBL / 128), dim3(256), 0, stream,
                     yg, opw, cC, cDI, (const void*)nullptr, flg, x1, x2,
                     (float*)nullptr);
  // 13. x3 = x2 + cpe2(x2)  (flg[2]=1 -> fp32 input path)
  hipLaunchKernelGGL(cpe_kernel, dim3(cpeBlocks), dim3(256), 0, stream,
                     x2, w2t, b2t, flg, 2, x3);
  // 14. xn2 = LN2(x3)
  hipLaunchKernelGGL(ln_kernel, dim3(cBL), dim3(256), 0, stream, x3, n2g, n2b, flg, xn2, cC);
  // 15. fc1 + gelu -> hbuf (MFMA)
  hipLaunchKernelGGL((gemm_mfma_kernel<3>), dim3(cHID / 64, cBL / 128), dim3(256), 0, stream,
                     xn2, f1w, cHID, cC, f1b, flg, (const float*)nullptr, hbuf,
                     (float*)nullptr);
  // 16. fc2 + bias + residual(x3) -> d_out fp32 (MFMA)
  hipLaunchKernelGGL((gemm_mfma_kernel<4>), dim3(cC / 64, cBL / 128), dim3(256), 0, stream,
                     hbuf, f2w, cC, cHID, f2b, flg, x3, (float*)d_out,
                     (float*)nullptr);
}

// Round 7
// 638.341 us; speedup vs baseline: 1.3802x; 1.3802x over previous
//
#include <hip/hip_runtime.h>
#include <hip/hip_bf16.h>

#define DEV __device__ __forceinline__

namespace {

constexpr int cB = 2, cT = 8, cH = 32, cW = 32, cC = 192;
constexpr int cDI = 384, cN = 16, cK = 4, cDTR = 12, cLT = 77, cHID = 768;
constexpr int cL  = cT * cH * cW;      // 8192
constexpr int cBL = cB * cL;           // 16384
constexpr int SEG = 128, SEGLEN = cL / SEG;   // 128 segments x 64 steps
constexpr int XROW = cDTR + 2 * cN;    // 44 live cols
constexpr int XSTR = 48;               // padded row stride (float4-aligned)

typedef __attribute__((ext_vector_type(8))) short bf16x8;
typedef __attribute__((ext_vector_type(4))) float f32x4;
typedef __attribute__((ext_vector_type(4))) short short4v;

// ---------- scalar helpers ----------
DEV float bfu2f(unsigned short u) { return __uint_as_float(((unsigned)u) << 16); }
DEV float ldsel(const void* p, size_t i, int f32) {
  return f32 ? ((const float*)p)[i] : bfu2f(((const unsigned short*)p)[i]);
}
template <int F32>
DEV float4 ld4(const void* p, size_t e) {   // e: element index, multiple of 4
  if (F32) return *(const float4*)((const float*)p + e);
  ushort4 u = *(const ushort4*)((const unsigned short*)p + e);
  return make_float4(bfu2f(u.x), bfu2f(u.y), bfu2f(u.z), bfu2f(u.w));
}
DEV short f2bf(float f) {   // RNE float->bf16 bits
  unsigned u = __float_as_uint(f);
  u += 0x7fffu + ((u >> 16) & 1u);
  return (short)(u >> 16);
}
DEV float siluf(float x) { return x / (1.f + __expf(-x)); }
DEV float softplusf(float x) { return (x > 20.f) ? x : __logf(1.f + __expf(x)); }
DEV float gelut(float x) {            // tanh-approx gelu (JAX default)
  float u = 0.7978845608028654f * (x + 0.044715f * x * x * x);
  float e = __expf(2.f * u);
  float th = 1.f - 2.f / (e + 1.f);
  return 0.5f * x * (1.f + th);
}

template <int BS>
DEV void blkreduce2(float& a, float& b) {
  __shared__ float ra[BS], rb[BS];
  int t = threadIdx.x;
  ra[t] = a; rb[t] = b; __syncthreads();
#pragma unroll
  for (int s = BS / 2; s > 0; s >>= 1) {
    if (t < s) { ra[t] += ra[t + s]; rb[t] += rb[t + s]; }
    __syncthreads();
  }
  a = ra[0]; b = rb[0];
  __syncthreads();
}

// ---------- dtype detector (validated: inputs are fp32) ----------
__global__ void __launch_bounds__(256) detect_kernel(
    const unsigned short* __restrict__ xa, const unsigned short* __restrict__ wp,
    int* __restrict__ flg) {
  __shared__ int cnt[2];
  if (threadIdx.x < 2) cnt[threadIdx.x] = 0;
  __syncthreads();
  int l0 = 0, l1 = 0;
  for (int i = threadIdx.x; i < 1024; i += 256) {
    float v = bfu2f(xa[2 * i]); float a = fabsf(v);
    if (v == 0.f || (a > 1e-8f && a < 1e4f)) l0++;
    float u = bfu2f(wp[2 * i]); float bq = fabsf(u);
    if (u == 0.f || (bq > 1e-8f && bq < 1e4f)) l1++;
  }
  atomicAdd(&cnt[0], l0); atomicAdd(&cnt[1], l1);
  __syncthreads();
  if (threadIdx.x == 0) {
    flg[0] = (cnt[0] < 614) ? 1 : 0;
    flg[1] = (cnt[1] < 614) ? 1 : 0;
    flg[2] = 1;
  }
}

// ---------- conv weight prep: transpose [Ch][27] -> [27][Ch] fp32, decode biases ----------
__global__ void __launch_bounds__(256) prep_kernel(
    const void* __restrict__ cvw, const void* __restrict__ cvb,
    const void* __restrict__ c1w, const void* __restrict__ c1b,
    const void* __restrict__ c2w, const void* __restrict__ c2b,
    const int* __restrict__ flg,
    float* __restrict__ wcv, float* __restrict__ bcv,
    float* __restrict__ w1, float* __restrict__ b1,
    float* __restrict__ w2, float* __restrict__ b2) {
  int pf = flg[1];
  int i = blockIdx.x * 256 + threadIdx.x;
  int r = i;
  if (r < 27 * cDI) { int j = r / cDI, d = r % cDI; wcv[r] = ldsel(cvw, (size_t)d * 27 + j, pf); return; }
  r -= 27 * cDI;
  if (r < cDI) { bcv[r] = ldsel(cvb, r, pf); return; }
  r -= cDI;
  if (r < 27 * cC) { int j = r / cC, c = r % cC; w1[r] = ldsel(c1w, (size_t)c * 27 + j, pf); return; }
  r -= 27 * cC;
  if (r < cC) { b1[r] = ldsel(c1b, r, pf); return; }
  r -= cC;
  if (r < 27 * cC) { int j = r / cC, c = r % cC; w2[r] = ldsel(c2w, (size_t)c * 27 + j, pf); return; }
  r -= 27 * cC;
  if (r < cC) { b2[r] = ldsel(c2b, r, pf); return; }
}

// ---------- CPE (depthwise 3x3x3 + residual), 4-channel vectorized ----------
template <int F32>
DEV void cpe_body(const void* __restrict__ xin, const float* __restrict__ wT,
                  const float* __restrict__ bs, int idx, float* __restrict__ out) {
  int c = (idx % (cC / 4)) * 4; int bv = idx / (cC / 4);
  int v = bv & (cL - 1); int b = bv >> 13;
  int t = v >> 10, q = v & 1023, h = q >> 5, w = q & 31;
  float4 acc = *(const float4*)(bs + c);
#pragma unroll
  for (int dz = 0; dz < 3; ++dz) {
    int tt = t + dz - 1; if ((unsigned)tt >= (unsigned)cT) continue;
#pragma unroll
    for (int dy = 0; dy < 3; ++dy) {
      int hh = h + dy - 1; if ((unsigned)hh >= (unsigned)cH) continue;
#pragma unroll
      for (int dx = 0; dx < 3; ++dx) {
        int ww = w + dx - 1; if ((unsigned)ww >= (unsigned)cW) continue;
        int vv = (tt << 10) + (hh << 5) + ww;
        float4 wv = *(const float4*)(wT + (dz * 9 + dy * 3 + dx) * cC + c);
        float4 xv = ld4<F32>(xin, ((size_t)b * cL + vv) * cC + c);
        acc.x += wv.x * xv.x; acc.y += wv.y * xv.y;
        acc.z += wv.z * xv.z; acc.w += wv.w * xv.w;
      }
    }
  }
  float4 x0 = ld4<F32>(xin, (size_t)bv * cC + c);
  float4 o = make_float4(x0.x + acc.x, x0.y + acc.y, x0.z + acc.z, x0.w + acc.w);
  *(float4*)(out + (size_t)bv * cC + c) = o;
}

__global__ void __launch_bounds__(256) cpe_kernel(
    const void* __restrict__ xin, const float* __restrict__ wT,
    const float* __restrict__ bs, const int* __restrict__ flg, int afidx,
    float* __restrict__ out) {
  int idx = blockIdx.x * 256 + threadIdx.x;
  if (idx >= cBL * cC / 4) return;
  if (flg[afidx]) cpe_body<1>(xin, wT, bs, idx, out);
  else            cpe_body<0>(xin, wT, bs, idx, out);
}

// ---------- depthwise conv on DI + SiLU -> bf16 output ----------
__global__ void __launch_bounds__(256) dwconv_silu_kernel(
    const float* __restrict__ xin, const float* __restrict__ wT,
    const float* __restrict__ bs, unsigned short* __restrict__ out) {
  int idx = blockIdx.x * 256 + threadIdx.x;
  if (idx >= cBL * cDI / 4) return;
  int d = (idx % (cDI / 4)) * 4; int bv = idx / (cDI / 4);
  int v = bv & (cL - 1); int b = bv >> 13;
  int t = v >> 10, q = v & 1023, h = q >> 5, w = q & 31;
  float4 acc = *(const float4*)(bs + d);
#pragma unroll
  for (int dz = 0; dz < 3; ++dz) {
    int tt = t + dz - 1; if ((unsigned)tt >= (unsigned)cT) continue;
#pragma unroll
    for (int dy = 0; dy < 3; ++dy) {
      int hh = h + dy - 1; if ((unsigned)hh >= (unsigned)cH) continue;
#pragma unroll
      for (int dx = 0; dx < 3; ++dx) {
        int ww = w + dx - 1; if ((unsigned)ww >= (unsigned)cW) continue;
        int vv = (tt << 10) + (hh << 5) + ww;
        float4 wv = *(const float4*)(wT + (dz * 9 + dy * 3 + dx) * cDI + d);
        float4 xv = *(const float4*)(xin + ((size_t)b * cL + vv) * cDI + d);
        acc.x += wv.x * xv.x; acc.y += wv.y * xv.y;
        acc.z += wv.z * xv.z; acc.w += wv.w * xv.w;
      }
    }
  }
  ushort4 o;
  o.x = (unsigned short)f2bf(siluf(acc.x));
  o.y = (unsigned short)f2bf(siluf(acc.y));
  o.z = (unsigned short)f2bf(siluf(acc.z));
  o.w = (unsigned short)f2bf(siluf(acc.w));
  *(ushort4*)(out + (size_t)bv * cDI + d) = o;
}

// ---------- row LayerNorm ----------
__global__ void __launch_bounds__(256) ln_kernel(
    const float* __restrict__ in, const void* __restrict__ g,
    const void* __restrict__ bb, const int* __restrict__ flg,
    float* __restrict__ out, int D) {
  int pf = flg[1];
  int row = blockIdx.x;
  const float* x = in + (size_t)row * D;
  float s1 = 0.f, s2 = 0.f;
  for (int i = threadIdx.x; i < D; i += 256) { float v = x[i]; s1 += v; s2 += v * v; }
  blkreduce2<256>(s1, s2);
  float mean = s1 / D;
  float var = s2 / D - mean * mean;
  float rstd = rsqrtf(var + 1e-6f);
  float* o = out + (size_t)row * D;
  for (int i = threadIdx.x; i < D; i += 256)
    o[i] = (x[i] - mean) * rstd * ldsel(g, i, pf) + ldsel(bb, i, pf);
}

// ---------- text conditioning ----------
__global__ void __launch_bounds__(384) text_cond_kernel(
    const void* __restrict__ text, const void* __restrict__ tw,
    const void* __restrict__ tb, const int* __restrict__ flg,
    float* __restrict__ cond) {
  int af = flg[0], pf = flg[1];
  __shared__ float mean[cC];
  int b = blockIdx.x;
  for (int c = threadIdx.x; c < cC; c += 384) {
    float s = 0.f;
    for (int t = 0; t < cLT; ++t) s += ldsel(text, ((size_t)b * cLT + t) * cC + c, af);
    mean[c] = s * (1.f / cLT);
  }
  __syncthreads();
  int di = threadIdx.x;
  float a = ldsel(tb, di, pf);
  for (int c = 0; c < cC; ++c) a += mean[c] * ldsel(tw, di * cC + c, pf);
  cond[b * cDI + di] = siluf(a);
}

// ---------- MFMA GEMM: out = epilogue(A[M,K] @ W[N,K]^T), bf16 compute ----------
// ABF=1: A is bf16 (direct LDS copy, no convert). MODE 0 stores z as bf16 out2.
template <int MODE, int ABF>
__global__ void __launch_bounds__(256) gemm_mfma_kernel(
    const void* __restrict__ A, const void* __restrict__ W,
    int N, int K, const void* __restrict__ bias, const int* __restrict__ flg,
    const float* __restrict__ extra, float* __restrict__ out,
    unsigned short* __restrict__ out2) {
  constexpr int BM = 128, BN = 64, BK = 32, PK = 40;
  __shared__ short As[BM * PK];
  __shared__ short Bs[BN * PK];
  int pf = flg[1];
  int tid = threadIdx.x;
  int m0 = blockIdx.y * BM, n0 = blockIdx.x * BN;
  int lane = tid & 63, wv = tid >> 6;
  int wm = (wv >> 1) * 64, wn = (wv & 1) * 32;
  int lr = lane & 15, quad = lane >> 4;
  f32x4 acc[4][2];
#pragma unroll
  for (int mi = 0; mi < 4; ++mi)
#pragma unroll
    for (int ni = 0; ni < 2; ++ni) { acc[mi][ni][0]=0.f; acc[mi][ni][1]=0.f; acc[mi][ni][2]=0.f; acc[mi][ni][3]=0.f; }
  int ar = tid >> 1, aks = (tid & 1) * 16;
  int wr = tid >> 2, wks = (tid & 3) * 8;
  for (int k0 = 0; k0 < K; k0 += BK) {
    if (ABF) {
      const unsigned short* ap = (const unsigned short*)A + (size_t)(m0 + ar) * K + k0 + aks;
      short* da = &As[ar * PK + aks];
#pragma unroll
      for (int i = 0; i < 4; ++i)
        *(short4v*)(da + i * 4) = *(const short4v*)(ap + i * 4);
    } else {
      const float* ap = (const float*)A + (size_t)(m0 + ar) * K + k0 + aks;
      short* da = &As[ar * PK + aks];
#pragma unroll
      for (int i = 0; i < 4; ++i) {
        float4 v = ((const float4*)ap)[i];
        short4v h; h.x = f2bf(v.x); h.y = f2bf(v.y); h.z = f2bf(v.z); h.w = f2bf(v.w);
        *(short4v*)(da + i * 4) = h;
      }
    }
    {
      int nr = n0 + wr;
      short hb[8];
      if (nr < N) {
        size_t wi = (size_t)nr * K + k0 + wks;
        if (pf) {
#pragma unroll
          for (int i = 0; i < 8; ++i) hb[i] = f2bf(((const float*)W)[wi + i]);
        } else {
#pragma unroll
          for (int i = 0; i < 8; ++i) hb[i] = (short)((const unsigned short*)W)[wi + i];
        }
      } else {
#pragma unroll
        for (int i = 0; i < 8; ++i) hb[i] = 0;
      }
      short* db = &Bs[wr * PK + wks];
#pragma unroll
      for (int i = 0; i < 8; i += 4) {
        short4v h; h.x = hb[i]; h.y = hb[i+1]; h.z = hb[i+2]; h.w = hb[i+3];
        *(short4v*)(db + i) = h;
      }
    }
    __syncthreads();
    bf16x8 af[4], bfr[2];
#pragma unroll
    for (int mi = 0; mi < 4; ++mi)
      af[mi] = *(const bf16x8*)&As[(wm + mi * 16 + lr) * PK + quad * 8];
#pragma unroll
    for (int ni = 0; ni < 2; ++ni)
      bfr[ni] = *(const bf16x8*)&Bs[(wn + ni * 16 + lr) * PK + quad * 8];
#pragma unroll
    for (int mi = 0; mi < 4; ++mi)
#pragma unroll
      for (int ni = 0; ni < 2; ++ni)
        acc[mi][ni] = __builtin_amdgcn_mfma_f32_16x16x32_bf16(af[mi], bfr[ni], acc[mi][ni], 0, 0, 0);
    __syncthreads();
  }
#pragma unroll
  for (int mi = 0; mi < 4; ++mi) {
#pragma unroll
    for (int ni = 0; ni < 2; ++ni) {
#pragma unroll
      for (int r = 0; r < 4; ++r) {
        int m = m0 + wm + mi * 16 + quad * 4 + r;
        int n = n0 + wn + ni * 16 + lr;
        float v = acc[mi][ni][r];
        if (MODE == 0) {
          float bvv = ldsel(bias, n, pf);
          int b = m >> 13;
          if (n < cDI) out[(size_t)m * cDI + n] = v + bvv + extra[b * cDI + n];
          else         out2[(size_t)m * cDI + (n - cDI)] = (unsigned short)f2bf(v + bvv);
        } else if (MODE == 1) {
          if (n < cK * XROW) {
            int k = n / XROW, c = n - k * XROW;
            int b = m >> 13, vv = m & (cL - 1);
            int t = vv >> 10, q = vv & 1023, h = q >> 5, w = q & 31;
            int l1 = (t << 10) + (w << 5) + h;
            int lk = (k == 0) ? vv : (k == 1) ? l1 : (k == 2) ? (cL - 1 - vv) : (cL - 1 - l1);
            out[((size_t)(b * cK + k) * cL + lk) * XSTR + c] = v;
          }
        } else if (MODE == 2) {
          out[(size_t)m * cC + n] = v + extra[(size_t)m * cC + n];
        } else if (MODE == 3) {
          out[(size_t)m * cHID + n] = gelut(v + ldsel(bias, n, pf));
        } else {
          out[(size_t)m * cC + n] = v + ldsel(bias, n, pf) + extra[(size_t)m * cC + n];
        }
      }
    }
  }
}

// voxel index for scan position l in direction k
DEV int scan_voxel(int k, int l) {
  if (k == 0) return l;
  if (k == 2) return cL - 1 - l;
  int ll = (k == 1) ? l : (cL - 1 - l);
  int t = ll >> 10, q = ll & 1023, w = q >> 5, h = q & 31;
  return (t << 10) + (h << 5) + w;
}

// ---------- register row structs (constant-indexed, SROA-friendly) ----------
struct Row11 { float4 r0, r1, r2, r3, r4, r5, r6, r7, r8, r9, r10; };
struct Row7  { float4 r0, r1, r2, r7, r8, r9, r10; };

DEV Row11 ldrow11(const float* __restrict__ rows, int st) {
  const float4* rp = (const float4*)(rows + st * XSTR);
  Row11 q;
  q.r0 = rp[0]; q.r1 = rp[1]; q.r2 = rp[2]; q.r3 = rp[3]; q.r4 = rp[4];
  q.r5 = rp[5]; q.r6 = rp[6]; q.r7 = rp[7]; q.r8 = rp[8]; q.r9 = rp[9];
  q.r10 = rp[10];
  return q;
}
DEV Row7 ldrow7(const float* __restrict__ rows, int st) {
  const float4* rp = (const float4*)(rows + st * XSTR);
  Row7 q;
  q.r0 = rp[0]; q.r1 = rp[1]; q.r2 = rp[2];
  q.r7 = rp[7]; q.r8 = rp[8]; q.r9 = rp[9]; q.r10 = rp[10];
  return q;
}

// one fast-path scan1 step: consumes q (row regs) + u, updates h/P1, returns y
DEV float s1step(const Row11& q, float u,
                 const float (&wdt)[cDTR], float dtb, float ac0, float Dsd,
                 float (&h)[cN], float& P1) {
  float s0 = dtb + q.r0.x*wdt[0] + q.r0.z*wdt[2] + q.r1.x*wdt[4] + q.r1.z*wdt[6] + q.r2.x*wdt[8] + q.r2.z*wdt[10];
  float s1 = q.r0.y*wdt[1] + q.r0.w*wdt[3] + q.r1.y*wdt[5] + q.r1.w*wdt[7] + q.r2.y*wdt[9] + q.r2.w*wdt[11];
  float dt = softplusf(s0 + s1);
  float a1 = exp2f(dt * ac0);
  float a2 = a1*a1, a3 = a2*a1, a4 = a2*a2;
  float a5 = a4*a1, a6 = a4*a2, a7 = a4*a3, a8 = a4*a4;
  float a9 = a8*a1, a10 = a8*a2, a11 = a8*a3, a12 = a8*a4;
  float a13 = a8*a5, a14 = a8*a6, a15 = a8*a7, a16 = a8*a8;
  float dtu = dt * u;
  P1 *= a1;
  float yp0 = Dsd * u, yp1 = 0.f, yp2 = 0.f, yp3 = 0.f;
  h[0]  = h[0] *a1  + dtu*q.r3.x; yp0 += h[0] *q.r7.x;
  h[1]  = h[1] *a2  + dtu*q.r3.y; yp1 += h[1] *q.r7.y;
  h[2]  = h[2] *a3  + dtu*q.r3.z; yp2 += h[2] *q.r7.z;
  h[3]  = h[3] *a4  + dtu*q.r3.w; yp3 += h[3] *q.r7.w;
  h[4]  = h[4] *a5  + dtu*q.r4.x; yp0 += h[4] *q.r8.x;
  h[5]  = h[5] *a6  + dtu*q.r4.y; yp1 += h[5] *q.r8.y;
  h[6]  = h[6] *a7  + dtu*q.r4.z; yp2 += h[6] *q.r8.z;
  h[7]  = h[7] *a8  + dtu*q.r4.w; yp3 += h[7] *q.r8.w;
  h[8]  = h[8] *a9  + dtu*q.r5.x; yp0 += h[8] *q.r9.x;
  h[9]  = h[9] *a10 + dtu*q.r5.y; yp1 += h[9] *q.r9.y;
  h[10] = h[10]*a11 + dtu*q.r5.z; yp2 += h[10]*q.r9.z;
  h[11] = h[11]*a12 + dtu*q.r5.w; yp3 += h[11]*q.r9.w;
  h[12] = h[12]*a13 + dtu*q.r6.x; yp0 += h[12]*q.r10.x;
  h[13] = h[13]*a14 + dtu*q.r6.y; yp1 += h[13]*q.r10.y;
  h[14] = h[14]*a15 + dtu*q.r6.z; yp2 += h[14]*q.r10.z;
  h[15] = h[15]*a16 + dtu*q.r6.w; yp3 += h[15]*q.r10.w;
  return (yp0 + yp1) + (yp2 + yp3);
}

// one fast-path scan3 step: evolves g, returns correction y
DEV float s3step(const Row7& q,
                 const float (&wdt)[cDTR], float dtb, float ac0,
                 float (&g)[cN]) {
  float s0 = dtb + q.r0.x*wdt[0] + q.r0.z*wdt[2] + q.r1.x*wdt[4] + q.r1.z*wdt[6] + q.r2.x*wdt[8] + q.r2.z*wdt[10];
  float s1 = q.r0.y*wdt[1] + q.r0.w*wdt[3] + q.r1.y*wdt[5] + q.r1.w*wdt[7] + q.r2.y*wdt[9] + q.r2.w*wdt[11];
  float dt = softplusf(s0 + s1);
  float a1 = exp2f(dt * ac0);
  float a2 = a1*a1, a3 = a2*a1, a4 = a2*a2;
  float a5 = a4*a1, a6 = a4*a2, a7 = a4*a3, a8 = a4*a4;
  float a9 = a8*a1, a10 = a8*a2, a11 = a8*a3, a12 = a8*a4;
  float a13 = a8*a5, a14 = a8*a6, a15 = a8*a7, a16 = a8*a8;
  float yp0 = 0.f, yp1 = 0.f, yp2 = 0.f, yp3 = 0.f;
  g[0]  *= a1;  yp0 += g[0] *q.r7.x;
  g[1]  *= a2;  yp1 += g[1] *q.r7.y;
  g[2]  *= a3;  yp2 += g[2] *q.r7.z;
  g[3]  *= a4;  yp3 += g[3] *q.r7.w;
  g[4]  *= a5;  yp0 += g[4] *q.r8.x;
  g[5]  *= a6;  yp1 += g[5] *q.r8.y;
  g[6]  *= a7;  yp2 += g[6] *q.r8.z;
  g[7]  *= a8;  yp3 += g[7] *q.r8.w;
  g[8]  *= a9;  yp0 += g[8] *q.r9.x;
  g[9]  *= a10; yp1 += g[9] *q.r9.y;
  g[10] *= a11; yp2 += g[10]*q.r9.z;
  g[11] *= a12; yp3 += g[11]*q.r9.w;
  g[12] *= a13; yp0 += g[12]*q.r10.x;
  g[13] *= a14; yp1 += g[13]*q.r10.y;
  g[14] *= a15; yp2 += g[14]*q.r10.z;
  g[15] *= a16; yp3 += g[15]*q.r10.w;
  return (yp0 + yp1) + (yp2 + yp3);
}

// ---------- scan pass 1 ----------
// r4 structure (128 thr, LDS rows, 2x ping-pong) but NO atomics: each (k,b,l)
// position is uniquely owned, so y is written with plain streaming bf16 stores
// into a per-direction l-ordered buffer. merge gathers the 4 directions later.
__global__ void __launch_bounds__(128, 3) scan1_kernel(
    const unsigned short* __restrict__ xch, const float* __restrict__ xdbl,
    const void* __restrict__ dtw, const void* __restrict__ dtbv,
    const void* __restrict__ alog, const void* __restrict__ dsv,
    const int* __restrict__ flg,
    unsigned short* __restrict__ ys0, unsigned short* __restrict__ ys1,
    unsigned short* __restrict__ ys2, unsigned short* __restrict__ ys3,
    unsigned short* __restrict__ hend, unsigned short* __restrict__ pend) {
  __shared__ float rows[SEGLEN * XSTR];   // 64 x 48 floats = 12 KB
  int pf = flg[1];
  int tid = threadIdx.x;
  int d = blockIdx.x * 128 + tid;
  int bks = blockIdx.y;
  int s = bks & (SEG - 1); int bk = bks / SEG; int k = bk & 3; int b = bk >> 2;
  int l0 = s * SEGLEN;
  {
    const float4* src = (const float4*)(xdbl + ((size_t)bk * cL + l0) * XSTR);
    float4* dst = (float4*)rows;
#pragma unroll
    for (int i = 0; i < (SEGLEN * XSTR / 4) / 128; ++i)   // 6 iters
      dst[tid + i * 128] = src[tid + i * 128];
  }
  float wdt[cDTR];
#pragma unroll
  for (int r = 0; r < cDTR; ++r) wdt[r] = ldsel(dtw, (size_t)(k * cDI + d) * cDTR + r, pf);
  float dtb = ldsel(dtbv, k * cDI + d, pf);
  float ac[cN];
#pragma unroll
  for (int n = 0; n < cN; ++n)
    ac[n] = -__expf(ldsel(alog, (size_t)(k * cDI + d) * cN + n, pf)) * 1.4426950408889634f;
  bool fast = true;
#pragma unroll
  for (int n = 1; n < cN; ++n)
    fast = fast && (fabsf(ac[n] - (float)(n + 1) * ac[0]) <= 1e-3f * fabsf(ac[n]));
  float Dsd = ldsel(dsv, k * cDI + d, pf);
  float h[cN];
#pragma unroll
  for (int n = 0; n < cN; ++n) h[n] = 0.f;
  size_t so = ((size_t)bks * cDI + d) * cN;
  const unsigned short* xcb = xch + (size_t)b * cL * cDI + d;
  unsigned short* ysk = (k == 0) ? ys0 : (k == 1) ? ys1 : (k == 2) ? ys2 : ys3;
  unsigned short* ysrow = ysk + ((size_t)b * cL + l0) * cDI + d;
  __syncthreads();
  if (fast) {
    float ac0 = ac[0];
    float P1 = 1.f;
    Row11 qa = ldrow11(rows, 0);
    float u0 = bfu2f(xcb[(size_t)scan_voxel(k, l0) * cDI]);
    float u1 = bfu2f(xcb[(size_t)scan_voxel(k, l0 + 1) * cDI]);
    for (int st = 0; st < SEGLEN; st += 2) {
      Row11 qb = ldrow11(rows, st + 1);
      int p2 = (st + 2 < SEGLEN) ? st + 2 : SEGLEN - 1;
      int p3 = (st + 3 < SEGLEN) ? st + 3 : SEGLEN - 1;
      float nu0 = bfu2f(xcb[(size_t)scan_voxel(k, l0 + p2) * cDI]);
      float nu1 = bfu2f(xcb[(size_t)scan_voxel(k, l0 + p3) * cDI]);
      float ya = s1step(qa, u0, wdt, dtb, ac0, Dsd, h, P1);
      ysrow[(size_t)st * cDI] = (unsigned short)f2bf(ya);
      qa = ldrow11(rows, p2);
      float yb = s1step(qb, u1, wdt, dtb, ac0, Dsd, h, P1);
      ysrow[(size_t)(st + 1) * cDI] = (unsigned short)f2bf(yb);
      u0 = nu0; u1 = nu1;
    }
    float pp = P1;
#pragma unroll
    for (int n = 0; n < cN; ++n) {
      hend[so + n] = (unsigned short)f2bf(h[n]);
      pend[so + n] = (unsigned short)f2bf(pp);
      pp *= P1;
    }
  } else {
    float P[cN];
#pragma unroll
    for (int n = 0; n < cN; ++n) P[n] = 1.f;
    for (int st = 0; st < SEGLEN; ++st) {
      int l = l0 + st;
      const float4* rp = (const float4*)(rows + st * XSTR);
      float4 q0 = rp[0], q1 = rp[1], q2 = rp[2];
      float s0 = dtb + q0.x*wdt[0] + q0.z*wdt[2] + q1.x*wdt[4] + q1.z*wdt[6] + q2.x*wdt[8] + q2.z*wdt[10];
      float s1 = q0.y*wdt[1] + q0.w*wdt[3] + q1.y*wdt[5] + q1.w*wdt[7] + q2.y*wdt[9] + q2.w*wdt[11];
      float dt = softplusf(s0 + s1);
      float Bv[cN], Cv[cN];
      float4 qb0 = rp[3], qb1 = rp[4], qb2 = rp[5], qb3 = rp[6];
      float4 qc0 = rp[7], qc1 = rp[8], qc2 = rp[9], qc3 = rp[10];
      Bv[0]=qb0.x; Bv[1]=qb0.y; Bv[2]=qb0.z; Bv[3]=qb0.w;
      Bv[4]=qb1.x; Bv[5]=qb1.y; Bv[6]=qb1.z; Bv[7]=qb1.w;
      Bv[8]=qb2.x; Bv[9]=qb2.y; Bv[10]=qb2.z; Bv[11]=qb2.w;
      Bv[12]=qb3.x; Bv[13]=qb3.y; Bv[14]=qb3.z; Bv[15]=qb3.w;
      Cv[0]=qc0.x; Cv[1]=qc0.y; Cv[2]=qc0.z; Cv[3]=qc0.w;
      Cv[4]=qc1.x; Cv[5]=qc1.y; Cv[6]=qc1.z; Cv[7]=qc1.w;
      Cv[8]=qc2.x; Cv[9]=qc2.y; Cv[10]=qc2.z; Cv[11]=qc2.w;
      Cv[12]=qc3.x; Cv[13]=qc3.y; Cv[14]=qc3.z; Cv[15]=qc3.w;
      int v = scan_voxel(k, l);
      float u = bfu2f(xcb[(size_t)v * cDI]);
      float dtu = dt * u;
      float y = Dsd * u;
#pragma unroll
      for (int n = 0; n < cN; ++n) {
        float a = exp2f(dt * ac[n]);
        h[n] = h[n] * a + dtu * Bv[n];
        P[n] *= a;
        y += h[n] * Cv[n];
      }
      ysrow[(size_t)st * cDI] = (unsigned short)f2bf(y);
    }
#pragma unroll
    for (int n = 0; n < cN; ++n) {
      hend[so + n] = (unsigned short)f2bf(h[n]);
      pend[so + n] = (unsigned short)f2bf(P[n]);
    }
  }
}

// ---------- scan pass 2 (serial prefix over segments; fp32 recurrence, bf16 storage) ----------
__global__ void __launch_bounds__(256) scan2_kernel(
    unsigned short* __restrict__ hend, const unsigned short* __restrict__ pend) {
  int tid = blockIdx.x * 256 + threadIdx.x;
  int bk = tid / (cDI * cN); int r = tid - bk * (cDI * cN);
  float g = 0.f;
  for (int s = 0; s < SEG; ++s) {
    size_t o = ((size_t)(bk * SEG + s) * cDI * cN) + r;
    float he = bfu2f(hend[o]), pe = bfu2f(pend[o]);
    hend[o] = (unsigned short)f2bf(g);
    g = pe * g + he;
  }
}

// ---------- scan pass 3 (owned read-add-store on l-ordered rows; no atomics) ----------
__global__ void __launch_bounds__(128, 3) scan3_kernel(
    const float* __restrict__ xdbl,
    const void* __restrict__ dtw, const void* __restrict__ dtbv,
    const void* __restrict__ alog, const int* __restrict__ flg,
    const unsigned short* __restrict__ hin,
    unsigned short* __restrict__ ys0, unsigned short* __restrict__ ys1,
    unsigned short* __restrict__ ys2, unsigned short* __restrict__ ys3) {
  int bks = blockIdx.y;
  int s = bks & (SEG - 1);
  if (s == 0) return;
  __shared__ float rows[SEGLEN * XSTR];
  int pf = flg[1];
  int tid = threadIdx.x;
  int d = blockIdx.x * 128 + tid;
  int bk = bks / SEG; int k = bk & 3; int b = bk >> 2;
  int l0 = s * SEGLEN;
  {
    const float4* src = (const float4*)(xdbl + ((size_t)bk * cL + l0) * XSTR);
    float4* dst = (float4*)rows;
#pragma unroll
    for (int i = 0; i < (SEGLEN * XSTR / 4) / 128; ++i)
      dst[tid + i * 128] = src[tid + i * 128];
  }
  float wdt[cDTR];
#pragma unroll
  for (int r = 0; r < cDTR; ++r) wdt[r] = ldsel(dtw, (size_t)(k * cDI + d) * cDTR + r, pf);
  float dtb = ldsel(dtbv, k * cDI + d, pf);
  float ac[cN];
#pragma unroll
  for (int n = 0; n < cN; ++n)
    ac[n] = -__expf(ldsel(alog, (size_t)(k * cDI + d) * cN + n, pf)) * 1.4426950408889634f;
  bool fast = true;
#pragma unroll
  for (int n = 1; n < cN; ++n)
    fast = fast && (fabsf(ac[n] - (float)(n + 1) * ac[0]) <= 1e-3f * fabsf(ac[n]));
  float g[cN];
  size_t so = ((size_t)bks * cDI + d) * cN;
#pragma unroll
  for (int n = 0; n < cN; ++n) g[n] = bfu2f(hin[so + n]);
  unsigned short* ysk = (k == 0) ? ys0 : (k == 1) ? ys1 : (k == 2) ? ys2 : ys3;
  unsigned short* ysrow = ysk + ((size_t)b * cL + l0) * cDI + d;
  __syncthreads();
  if (fast) {
    float ac0 = ac[0];
    Row7 qa = ldrow7(rows, 0);
    for (int st = 0; st < SEGLEN; st += 2) {
      Row7 qb = ldrow7(rows, st + 1);
      int p2 = (st + 2 < SEGLEN) ? st + 2 : SEGLEN - 1;
      float ya = s3step(qa, wdt, dtb, ac0, g);
      size_t ia = (size_t)st * cDI;
      ysrow[ia] = (unsigned short)f2bf(bfu2f(ysrow[ia]) + ya);
      qa = ldrow7(rows, p2);
      float yb = s3step(qb, wdt, dtb, ac0, g);
      size_t ib = (size_t)(st + 1) * cDI;
      ysrow[ib] = (unsigned short)f2bf(bfu2f(ysrow[ib]) + yb);
    }
  } else {
    for (int st = 0; st < SEGLEN; ++st) {
      const float4* rp = (const float4*)(rows + st * XSTR);
      float4 q0 = rp[0], q1 = rp[1], q2 = rp[2];
      float s0 = dtb + q0.x*wdt[0] + q0.z*wdt[2] + q1.x*wdt[4] + q1.z*wdt[6] + q2.x*wdt[8] + q2.z*wdt[10];
      float s1 = q0.y*wdt[1] + q0.w*wdt[3] + q1.y*wdt[5] + q1.w*wdt[7] + q2.y*wdt[9] + q2.w*wdt[11];
      float dt = softplusf(s0 + s1);
      float Cv[cN];
      float4 qc0 = rp[7], qc1 = rp[8], qc2 = rp[9], qc3 = rp[10];
      Cv[0]=qc0.x; Cv[1]=qc0.y; Cv[2]=qc0.z; Cv[3]=qc0.w;
      Cv[4]=qc1.x; Cv[5]=qc1.y; Cv[6]=qc1.z; Cv[7]=qc1.w;
      Cv[8]=qc2.x; Cv[9]=qc2.y; Cv[10]=qc2.z; Cv[11]=qc2.w;
      Cv[12]=qc3.x; Cv[13]=qc3.y; Cv[14]=qc3.z; Cv[15]=qc3.w;
      float y = 0.f;
#pragma unroll
      for (int n = 0; n < cN; ++n) {
        float a = exp2f(dt * ac[n]);
        g[n] *= a;
        y += g[n] * Cv[n];
      }
      size_t ii = (size_t)st * cDI;
      ysrow[ii] = (unsigned short)f2bf(bfu2f(ysrow[ii]) + y);
    }
  }
}

// ---------- merge: gather 4 directions + out_norm LN + silu(z) gate ----------
__global__ void __launch_bounds__(128) merge_kernel(
    const unsigned short* __restrict__ ys0, const unsigned short* __restrict__ ys1,
    const unsigned short* __restrict__ ys2, const unsigned short* __restrict__ ys3,
    const unsigned short* __restrict__ zh,
    const void* __restrict__ ong, const void* __restrict__ onb,
    const int* __restrict__ flg, unsigned short* __restrict__ yg) {
  int pf = flg[1];
  int bv = blockIdx.x;
  int v = bv & (cL - 1); int b = bv >> 13;
  int t = v >> 10, q = v & 1023, hh = q >> 5, ww = q & 31;
  int l1 = (t << 10) + (ww << 5) + hh;
  size_t r0 = ((size_t)b * cL + v) * cDI;
  size_t r1 = ((size_t)b * cL + l1) * cDI;
  size_t r2 = ((size_t)b * cL + (cL - 1 - v)) * cDI;
  size_t r3 = ((size_t)b * cL + (cL - 1 - l1)) * cDI;
  float vals[3]; float s1 = 0.f, s2 = 0.f;
#pragma unroll
  for (int i = 0; i < 3; ++i) {
    int d = threadIdx.x + i * 128;
    float x = bfu2f(ys0[r0 + d]) + bfu2f(ys1[r1 + d]) +
              bfu2f(ys2[r2 + d]) + bfu2f(ys3[r3 + d]);
    vals[i] = x; s1 += x; s2 += x * x;
  }
  blkreduce2<128>(s1, s2);
  float mean = s1 * (1.f / cDI);
  float var = s2 * (1.f / cDI) - mean * mean;
  float rstd = rsqrtf(var + 1e-6f);
  const unsigned short* zr = zh + (size_t)bv * cDI;
  unsigned short* og = yg + (size_t)bv * cDI;
#pragma unroll
  for (int i = 0; i < 3; ++i) {
    int d = threadIdx.x + i * 128;
    float xn = (vals[i] - mean) * rstd * ldsel(ong, d, pf) + ldsel(onb, d, pf);
    og[d] = (unsigned short)f2bf(xn * siluf(bfu2f(zr[d])));
  }
}

}  // namespace

extern "C" void kernel_launch(void* const* d_in, const int* in_sizes, int n_in,
                              void* d_out, int out_size, void* d_ws, size_t ws_size,
                              hipStream_t stream) {
  (void)in_sizes; (void)n_in; (void)out_size; (void)ws_size;
  const void* x    = d_in[0];
  const void* text = d_in[1];
  const void* c1w  = d_in[2];
  const void* c1b  = d_in[3];
  const void* c2w  = d_in[4];
  const void* c2b  = d_in[5];
  const void* n1g  = d_in[6];
  const void* n1b  = d_in[7];
  const void* n2g  = d_in[8];
  const void* n2b  = d_in[9];
  const void* ipw  = d_in[10];
  const void* ipb  = d_in[11];
  const void* tpw  = d_in[12];
  const void* tpb  = d_in[13];
  const void* cvw  = d_in[14];
  const void* cvb  = d_in[15];
  const void* xpw  = d_in[16];
  const void* dtw  = d_in[17];
  const void* dtb  = d_in[18];
  const void* alog = d_in[19];
  const void* dsv  = d_in[20];
  const void* ong  = d_in[21];
  const void* onb  = d_in[22];
  const void* opw  = d_in[23];
  const void* f1w  = d_in[24];
  const void* f1b  = d_in[25];
  const void* f2w  = d_in[26];
  const void* f2b  = d_in[27];

  float* Wf = (float*)d_ws;

  // ---- slot arena (~125.9 MB), atomic-free scan layout ----
  // oC lower: xc bf16 (6.29M ushort). oC upper: ystream dir2 (6.29M ushort).
  // oD: xdbl fp32 -> (after scan3) yg bf16. oG: xn fp32 -> pend bf16.
  // oA: ystream dirs 0,1 (12.58M ushort) -> x2 fp32.
  // oB lower: z bf16. oB upper: ystream dir3. -> x3 fp32 after merge.
  // oE: x1 fp32. oF: hend bf16 -> xn2 fp32. hbuf fp32 spans [0, 12.58M).
  constexpr size_t oC  = 0;                              // 6,291,456
  constexpr size_t oD  = 6291456;                        // 3,145,728
  constexpr size_t oG  = 9437184;                        // 3,145,728
  constexpr size_t oA  = 12582912;                       // 6,291,456
  constexpr size_t oB  = 18874368;                       // 6,291,456
  constexpr size_t oE  = 25165824;                       // 3,145,728
  constexpr size_t oF  = 28311552;                       // 3,145,728
  constexpr size_t oCO = 31457280;                       // 768 (cond)
  constexpr size_t oFL = 31458048;                       // 4 ints (flags)
  constexpr size_t oWCV = 31458052;                      // 27*384
  constexpr size_t oBCV = 31468420;                      // 384
  constexpr size_t oW1  = 31468804;                      // 27*192
  constexpr size_t oB1  = 31473988;                      // 192
  constexpr size_t oW2  = 31474180;                      // 5184
  constexpr size_t oB2  = 31479364;                      // 192 -> end 31479556
  unsigned short* xch = (unsigned short*)(Wf + oC);            // bf16 silu(dwconv)
  unsigned short* ysd2 = (unsigned short*)(Wf + oC + 3145728); // ystream dir 2
  float* xdbl = Wf + oD;
  unsigned short* ygh  = (unsigned short*)(Wf + oD);           // yg bf16 (after xdbl dead)
  float* xn   = Wf + oG;
  unsigned short* pendp = (unsigned short*)(Wf + oG);          // bf16, after xn dead
  unsigned short* ysd0 = (unsigned short*)(Wf + oA);           // ystream dir 0
  unsigned short* ysd1 = (unsigned short*)(Wf + oA + 3145728); // ystream dir 1
  float* xi   = Wf + oA;   // in_proj x-output (dead before ystream written? see note)
  float* x2   = Wf + oA;   // out_proj output (after ystream dead)
  unsigned short* zh   = (unsigned short*)(Wf + oB);           // z bf16
  unsigned short* ysd3 = (unsigned short*)(Wf + oB + 3145728); // ystream dir 3
  float* x3   = Wf + oB;
  float* x1   = Wf + oE;
  unsigned short* hendp = (unsigned short*)(Wf + oF);          // bf16
  float* xn2  = Wf + oF;
  float* cond = Wf + oCO;
  float* hbuf = Wf + oC;   // fc1 output spans oC+oD+oG (12.58M floats)
  int*   flg  = (int*)(Wf + oFL);
  float* wcv = Wf + oWCV; float* bcv = Wf + oBCV;
  float* w1t = Wf + oW1;  float* b1t = Wf + oB1;
  float* w2t = Wf + oW2;  float* b2t = Wf + oB2;
  // NOTE: xi (fp32 @oA) is consumed by dwconv BEFORE scan1 writes ysd0/ysd1
  // into the same slot — kernel ordering serializes this reuse.

  const int cpeBlocks = (cBL * cC / 4) / 256;     // 3072
  const int dwBlocks  = (cBL * cDI / 4) / 256;    // 6144

  // 0. dtype detection + conv weight prep
  hipLaunchKernelGGL(detect_kernel, dim3(1), dim3(256), 0, stream,
                     (const unsigned short*)x, (const unsigned short*)ipw, flg);
  hipLaunchKernelGGL(prep_kernel, dim3(85), dim3(256), 0, stream,
                     cvw, cvb, c1w, c1b, c2w, c2b, flg, wcv, bcv, w1t, b1t, w2t, b2t);
  // 1. x1 = x + cpe1(x)
  hipLaunchKernelGGL(cpe_kernel, dim3(cpeBlocks), dim3(256), 0, stream,
                     x, w1t, b1t, flg, 0, x1);
  // 2. xn = LN1(x1)
  hipLaunchKernelGGL(ln_kernel, dim3(cBL), dim3(256), 0, stream, x1, n1g, n1b, flg, xn, cC);
  // 3. cond
  hipLaunchKernelGGL(text_cond_kernel, dim3(cB), dim3(384), 0, stream, text, tpw, tpb, flg, cond);
  // 4. in_proj (MFMA): xn -> xi (+cond) fp32, z bf16
  hipLaunchKernelGGL((gemm_mfma_kernel<0, 0>), dim3(2 * cDI / 64, cBL / 128), dim3(256), 0, stream,
                     xn, ipw, 2 * cDI, cC, ipb, flg, cond, xi, zh);
  // 5. xch = bf16(silu(dwconv(xi)))
  hipLaunchKernelGGL(dwconv_silu_kernel, dim3(dwBlocks), dim3(256), 0, stream,
                     xi, wcv, bcv, xch);
  // 6. x_proj (MFMA, bf16 A, scatter to padded scan rows)
  hipLaunchKernelGGL((gemm_mfma_kernel<1, 1>), dim3((cK * XROW + 63) / 64, cBL / 128), dim3(256), 0, stream,
                     xch, xpw, cK * XROW, cDI, (const void*)nullptr, flg,
                     (const float*)nullptr, xdbl, (unsigned short*)nullptr);
  // 7-9. chunked selective scan (atomic-free: plain bf16 streaming stores)
  hipLaunchKernelGGL(scan1_kernel, dim3(cDI / 128, cB * cK * SEG), dim3(128), 0, stream,
                     xch, xdbl, dtw, dtb, alog, dsv, flg,
                     ysd0, ysd1, ysd2, ysd3, hendp, pendp);
  hipLaunchKernelGGL(scan2_kernel, dim3(cB * cK * cDI * cN / 256), dim3(256), 0, stream,
                     hendp, pendp);
  hipLaunchKernelGGL(scan3_kernel, dim3(cDI / 128, cB * cK * SEG), dim3(128), 0, stream,
                     xdbl, dtw, dtb, alog, flg, hendp, ysd0, ysd1, ysd2, ysd3);
  // 10. merge: gather 4 dirs + out_norm + gate -> yg bf16
  hipLaunchKernelGGL(merge_kernel, dim3(cBL), dim3(128), 0, stream,
                     ysd0, ysd1, ysd2, ysd3, zh, ong, onb, flg, ygh);
  // 11. out_proj (bf16 A) + residual(x1) -> x2 fp32
  hipLaunchKernelGGL((gemm_mfma_kernel<2, 1>), dim3(cC / 64, cBL / 128), dim3(256), 0, stream,
                     ygh, opw, cC, cDI, (const void*)nullptr, flg, x1, x2,
                     (unsigned short*)nullptr);
  // 12. x3 = x2 + cpe2(x2)  (flg[2]=1 -> fp32 input path)
  hipLaunchKernelGGL(cpe_kernel, dim3(cpeBlocks), dim3(256), 0, stream,
                     x2, w2t, b2t, flg, 2, x3);
  // 13. xn2 = LN2(x3)
  hipLaunchKernelGGL(ln_kernel, dim3(cBL), dim3(256), 0, stream, x3, n2g, n2b, flg, xn2, cC);
  // 14. fc1 + gelu -> hbuf (MFMA)
  hipLaunchKernelGGL((gemm_mfma_kernel<3, 0>), dim3(cHID / 64, cBL / 128), dim3(256), 0, stream,
                     xn2, f1w, cHID, cC, f1b, flg, (const float*)nullptr, hbuf,
                     (unsigned short*)nullptr);
  // 15. fc2 + bias + residual(x3) -> d_out fp32 (MFMA)
  hipLaunchKernelGGL((gemm_mfma_kernel<4, 0>), dim3(cC / 64, cBL / 128), dim3(256), 0, stream,
                     hbuf, f2w, cC, cHID, f2b, flg, x3, (float*)d_out,
                     (unsigned short*)nullptr);
}

// Round 8
// 616.594 us; speedup vs baseline: 1.4289x; 1.0353x over previous
//
#include <hip/hip_runtime.h>
#include <hip/hip_bf16.h>

#define DEV __device__ __forceinline__

namespace {

constexpr int cB = 2, cT = 8, cH = 32, cW = 32, cC = 192;
constexpr int cDI = 384, cN = 16, cK = 4, cDTR = 12, cLT = 77, cHID = 768;
constexpr int cL  = cT * cH * cW;      // 8192
constexpr int cBL = cB * cL;           // 16384
constexpr int SEG = 128, SEGLEN = cL / SEG;   // 128 segments x 64 steps
constexpr int XROW = cDTR + 2 * cN;    // 44 live cols
constexpr int XSTR = 48;               // padded row stride (float4-aligned)

typedef __attribute__((ext_vector_type(8))) short bf16x8;
typedef __attribute__((ext_vector_type(4))) float f32x4;
typedef __attribute__((ext_vector_type(4))) short short4v;

// ---------- scalar helpers ----------
DEV float bfu2f(unsigned short u) { return __uint_as_float(((unsigned)u) << 16); }
DEV float ldsel(const void* p, size_t i, int f32) {
  return f32 ? ((const float*)p)[i] : bfu2f(((const unsigned short*)p)[i]);
}
template <int F32>
DEV float4 ld4(const void* p, size_t e) {   // e: element index, multiple of 4
  if (F32) return *(const float4*)((const float*)p + e);
  ushort4 u = *(const ushort4*)((const unsigned short*)p + e);
  return make_float4(bfu2f(u.x), bfu2f(u.y), bfu2f(u.z), bfu2f(u.w));
}
DEV short f2bf(float f) {   // RNE float->bf16 bits
  unsigned u = __float_as_uint(f);
  u += 0x7fffu + ((u >> 16) & 1u);
  return (short)(u >> 16);
}
DEV float siluf(float x) { return x / (1.f + __expf(-x)); }
DEV float softplusf(float x) { return (x > 20.f) ? x : __logf(1.f + __expf(x)); }
DEV float gelut(float x) {            // tanh-approx gelu (JAX default)
  float u = 0.7978845608028654f * (x + 0.044715f * x * x * x);
  float e = __expf(2.f * u);
  float th = 1.f - 2.f / (e + 1.f);
  return 0.5f * x * (1.f + th);
}

template <int BS>
DEV void blkreduce2(float& a, float& b) {
  __shared__ float ra[BS], rb[BS];
  int t = threadIdx.x;
  ra[t] = a; rb[t] = b; __syncthreads();
#pragma unroll
  for (int s = BS / 2; s > 0; s >>= 1) {
    if (t < s) { ra[t] += ra[t + s]; rb[t] += rb[t + s]; }
    __syncthreads();
  }
  a = ra[0]; b = rb[0];
  __syncthreads();
}

// ---------- dtype detector (validated: inputs are fp32) ----------
__global__ void __launch_bounds__(256) detect_kernel(
    const unsigned short* __restrict__ xa, const unsigned short* __restrict__ wp,
    int* __restrict__ flg) {
  __shared__ int cnt[2];
  if (threadIdx.x < 2) cnt[threadIdx.x] = 0;
  __syncthreads();
  int l0 = 0, l1 = 0;
  for (int i = threadIdx.x; i < 1024; i += 256) {
    float v = bfu2f(xa[2 * i]); float a = fabsf(v);
    if (v == 0.f || (a > 1e-8f && a < 1e4f)) l0++;
    float u = bfu2f(wp[2 * i]); float bq = fabsf(u);
    if (u == 0.f || (bq > 1e-8f && bq < 1e4f)) l1++;
  }
  atomicAdd(&cnt[0], l0); atomicAdd(&cnt[1], l1);
  __syncthreads();
  if (threadIdx.x == 0) {
    flg[0] = (cnt[0] < 614) ? 1 : 0;
    flg[1] = (cnt[1] < 614) ? 1 : 0;
    flg[2] = 1;
  }
}

// ---------- conv weight prep: transpose [Ch][27] -> [27][Ch] fp32, decode biases ----------
__global__ void __launch_bounds__(256) prep_kernel(
    const void* __restrict__ cvw, const void* __restrict__ cvb,
    const void* __restrict__ c1w, const void* __restrict__ c1b,
    const void* __restrict__ c2w, const void* __restrict__ c2b,
    const int* __restrict__ flg,
    float* __restrict__ wcv, float* __restrict__ bcv,
    float* __restrict__ w1, float* __restrict__ b1,
    float* __restrict__ w2, float* __restrict__ b2) {
  int pf = flg[1];
  int i = blockIdx.x * 256 + threadIdx.x;
  int r = i;
  if (r < 27 * cDI) { int j = r / cDI, d = r % cDI; wcv[r] = ldsel(cvw, (size_t)d * 27 + j, pf); return; }
  r -= 27 * cDI;
  if (r < cDI) { bcv[r] = ldsel(cvb, r, pf); return; }
  r -= cDI;
  if (r < 27 * cC) { int j = r / cC, c = r % cC; w1[r] = ldsel(c1w, (size_t)c * 27 + j, pf); return; }
  r -= 27 * cC;
  if (r < cC) { b1[r] = ldsel(c1b, r, pf); return; }
  r -= cC;
  if (r < 27 * cC) { int j = r / cC, c = r % cC; w2[r] = ldsel(c2w, (size_t)c * 27 + j, pf); return; }
  r -= 27 * cC;
  if (r < cC) { b2[r] = ldsel(c2b, r, pf); return; }
}

// ---------- CPE (depthwise 3x3x3 + residual), 4-channel vectorized ----------
template <int F32>
DEV void cpe_body(const void* __restrict__ xin, const float* __restrict__ wT,
                  const float* __restrict__ bs, int idx, float* __restrict__ out) {
  int c = (idx % (cC / 4)) * 4; int bv = idx / (cC / 4);
  int v = bv & (cL - 1); int b = bv >> 13;
  int t = v >> 10, q = v & 1023, h = q >> 5, w = q & 31;
  float4 acc = *(const float4*)(bs + c);
#pragma unroll
  for (int dz = 0; dz < 3; ++dz) {
    int tt = t + dz - 1; if ((unsigned)tt >= (unsigned)cT) continue;
#pragma unroll
    for (int dy = 0; dy < 3; ++dy) {
      int hh = h + dy - 1; if ((unsigned)hh >= (unsigned)cH) continue;
#pragma unroll
      for (int dx = 0; dx < 3; ++dx) {
        int ww = w + dx - 1; if ((unsigned)ww >= (unsigned)cW) continue;
        int vv = (tt << 10) + (hh << 5) + ww;
        float4 wv = *(const float4*)(wT + (dz * 9 + dy * 3 + dx) * cC + c);
        float4 xv = ld4<F32>(xin, ((size_t)b * cL + vv) * cC + c);
        acc.x += wv.x * xv.x; acc.y += wv.y * xv.y;
        acc.z += wv.z * xv.z; acc.w += wv.w * xv.w;
      }
    }
  }
  float4 x0 = ld4<F32>(xin, (size_t)bv * cC + c);
  float4 o = make_float4(x0.x + acc.x, x0.y + acc.y, x0.z + acc.z, x0.w + acc.w);
  *(float4*)(out + (size_t)bv * cC + c) = o;
}

__global__ void __launch_bounds__(256) cpe_kernel(
    const void* __restrict__ xin, const float* __restrict__ wT,
    const float* __restrict__ bs, const int* __restrict__ flg, int afidx,
    float* __restrict__ out) {
  int idx = blockIdx.x * 256 + threadIdx.x;
  if (idx >= cBL * cC / 4) return;
  if (flg[afidx]) cpe_body<1>(xin, wT, bs, idx, out);
  else            cpe_body<0>(xin, wT, bs, idx, out);
}

// ---------- depthwise conv on DI + SiLU: bf16 in -> bf16 out ----------
__global__ void __launch_bounds__(256) dwconv_silu_kernel(
    const unsigned short* __restrict__ xin, const float* __restrict__ wT,
    const float* __restrict__ bs, unsigned short* __restrict__ out) {
  int idx = blockIdx.x * 256 + threadIdx.x;
  if (idx >= cBL * cDI / 4) return;
  int d = (idx % (cDI / 4)) * 4; int bv = idx / (cDI / 4);
  int v = bv & (cL - 1); int b = bv >> 13;
  int t = v >> 10, q = v & 1023, h = q >> 5, w = q & 31;
  float4 acc = *(const float4*)(bs + d);
#pragma unroll
  for (int dz = 0; dz < 3; ++dz) {
    int tt = t + dz - 1; if ((unsigned)tt >= (unsigned)cT) continue;
#pragma unroll
    for (int dy = 0; dy < 3; ++dy) {
      int hh = h + dy - 1; if ((unsigned)hh >= (unsigned)cH) continue;
#pragma unroll
      for (int dx = 0; dx < 3; ++dx) {
        int ww = w + dx - 1; if ((unsigned)ww >= (unsigned)cW) continue;
        int vv = (tt << 10) + (hh << 5) + ww;
        float4 wv = *(const float4*)(wT + (dz * 9 + dy * 3 + dx) * cDI + d);
        ushort4 u4 = *(const ushort4*)(xin + ((size_t)b * cL + vv) * cDI + d);
        acc.x += wv.x * bfu2f(u4.x); acc.y += wv.y * bfu2f(u4.y);
        acc.z += wv.z * bfu2f(u4.z); acc.w += wv.w * bfu2f(u4.w);
      }
    }
  }
  ushort4 o;
  o.x = (unsigned short)f2bf(siluf(acc.x));
  o.y = (unsigned short)f2bf(siluf(acc.y));
  o.z = (unsigned short)f2bf(siluf(acc.z));
  o.w = (unsigned short)f2bf(siluf(acc.w));
  *(ushort4*)(out + (size_t)bv * cDI + d) = o;
}

// ---------- wave-per-row LayerNorm (C=192): no LDS, no barriers, bf16 out ----------
__global__ void __launch_bounds__(256) lnb_kernel(
    const float* __restrict__ in, const void* __restrict__ g,
    const void* __restrict__ bb, const int* __restrict__ flg,
    unsigned short* __restrict__ out) {
  int pf = flg[1];
  int row = blockIdx.x * 4 + (threadIdx.x >> 6);
  int lane = threadIdx.x & 63;
  const float* x = in + (size_t)row * cC;
  float v0 = x[lane], v1 = x[lane + 64], v2 = x[lane + 128];
  float s1 = v0 + v1 + v2;
  float s2 = v0 * v0 + v1 * v1 + v2 * v2;
#pragma unroll
  for (int off = 32; off > 0; off >>= 1) {
    s1 += __shfl_xor(s1, off);
    s2 += __shfl_xor(s2, off);
  }
  float mean = s1 * (1.f / cC);
  float var = s2 * (1.f / cC) - mean * mean;
  float rstd = rsqrtf(var + 1e-6f);
  unsigned short* o = out + (size_t)row * cC;
  o[lane]       = (unsigned short)f2bf((v0 - mean) * rstd * ldsel(g, lane, pf)       + ldsel(bb, lane, pf));
  o[lane + 64]  = (unsigned short)f2bf((v1 - mean) * rstd * ldsel(g, lane + 64, pf)  + ldsel(bb, lane + 64, pf));
  o[lane + 128] = (unsigned short)f2bf((v2 - mean) * rstd * ldsel(g, lane + 128, pf) + ldsel(bb, lane + 128, pf));
}

// ---------- text conditioning ----------
__global__ void __launch_bounds__(384) text_cond_kernel(
    const void* __restrict__ text, const void* __restrict__ tw,
    const void* __restrict__ tb, const int* __restrict__ flg,
    float* __restrict__ cond) {
  int af = flg[0], pf = flg[1];
  __shared__ float mean[cC];
  int b = blockIdx.x;
  for (int c = threadIdx.x; c < cC; c += 384) {
    float s = 0.f;
    for (int t = 0; t < cLT; ++t) s += ldsel(text, ((size_t)b * cLT + t) * cC + c, af);
    mean[c] = s * (1.f / cLT);
  }
  __syncthreads();
  int di = threadIdx.x;
  float a = ldsel(tb, di, pf);
  for (int c = 0; c < cC; ++c) a += mean[c] * ldsel(tw, di * cC + c, pf);
  cond[b * cDI + di] = siluf(a);
}

// ---------- MFMA GEMM: out = epilogue(A[M,K] @ W[N,K]^T), bf16 compute ----------
// ABF=1: A is bf16 (direct LDS copy). MODE 0: x-half AND z as bf16.
// MODE 3: bf16 gelu out. Epilogue casts handle the bf16 activation stores.
template <int MODE, int ABF>
__global__ void __launch_bounds__(256) gemm_mfma_kernel(
    const void* __restrict__ A, const void* __restrict__ W,
    int N, int K, const void* __restrict__ bias, const int* __restrict__ flg,
    const float* __restrict__ extra, float* __restrict__ out,
    unsigned short* __restrict__ out2) {
  constexpr int BM = 128, BN = 64, BK = 32, PK = 40;
  __shared__ short As[BM * PK];
  __shared__ short Bs[BN * PK];
  int pf = flg[1];
  int tid = threadIdx.x;
  int m0 = blockIdx.y * BM, n0 = blockIdx.x * BN;
  int lane = tid & 63, wv = tid >> 6;
  int wm = (wv >> 1) * 64, wn = (wv & 1) * 32;
  int lr = lane & 15, quad = lane >> 4;
  f32x4 acc[4][2];
#pragma unroll
  for (int mi = 0; mi < 4; ++mi)
#pragma unroll
    for (int ni = 0; ni < 2; ++ni) { acc[mi][ni][0]=0.f; acc[mi][ni][1]=0.f; acc[mi][ni][2]=0.f; acc[mi][ni][3]=0.f; }
  int ar = tid >> 1, aks = (tid & 1) * 16;
  int wr = tid >> 2, wks = (tid & 3) * 8;
  for (int k0 = 0; k0 < K; k0 += BK) {
    if (ABF) {
      const unsigned short* ap = (const unsigned short*)A + (size_t)(m0 + ar) * K + k0 + aks;
      short* da = &As[ar * PK + aks];
#pragma unroll
      for (int i = 0; i < 4; ++i)
        *(short4v*)(da + i * 4) = *(const short4v*)(ap + i * 4);
    } else {
      const float* ap = (const float*)A + (size_t)(m0 + ar) * K + k0 + aks;
      short* da = &As[ar * PK + aks];
#pragma unroll
      for (int i = 0; i < 4; ++i) {
        float4 v = ((const float4*)ap)[i];
        short4v h; h.x = f2bf(v.x); h.y = f2bf(v.y); h.z = f2bf(v.z); h.w = f2bf(v.w);
        *(short4v*)(da + i * 4) = h;
      }
    }
    {
      int nr = n0 + wr;
      short hb[8];
      if (nr < N) {
        size_t wi = (size_t)nr * K + k0 + wks;
        if (pf) {
#pragma unroll
          for (int i = 0; i < 8; ++i) hb[i] = f2bf(((const float*)W)[wi + i]);
        } else {
#pragma unroll
          for (int i = 0; i < 8; ++i) hb[i] = (short)((const unsigned short*)W)[wi + i];
        }
      } else {
#pragma unroll
        for (int i = 0; i < 8; ++i) hb[i] = 0;
      }
      short* db = &Bs[wr * PK + wks];
#pragma unroll
      for (int i = 0; i < 8; i += 4) {
        short4v h; h.x = hb[i]; h.y = hb[i+1]; h.z = hb[i+2]; h.w = hb[i+3];
        *(short4v*)(db + i) = h;
      }
    }
    __syncthreads();
    bf16x8 af[4], bfr[2];
#pragma unroll
    for (int mi = 0; mi < 4; ++mi)
      af[mi] = *(const bf16x8*)&As[(wm + mi * 16 + lr) * PK + quad * 8];
#pragma unroll
    for (int ni = 0; ni < 2; ++ni)
      bfr[ni] = *(const bf16x8*)&Bs[(wn + ni * 16 + lr) * PK + quad * 8];
#pragma unroll
    for (int mi = 0; mi < 4; ++mi)
#pragma unroll
      for (int ni = 0; ni < 2; ++ni)
        acc[mi][ni] = __builtin_amdgcn_mfma_f32_16x16x32_bf16(af[mi], bfr[ni], acc[mi][ni], 0, 0, 0);
    __syncthreads();
  }
#pragma unroll
  for (int mi = 0; mi < 4; ++mi) {
#pragma unroll
    for (int ni = 0; ni < 2; ++ni) {
#pragma unroll
      for (int r = 0; r < 4; ++r) {
        int m = m0 + wm + mi * 16 + quad * 4 + r;
        int n = n0 + wn + ni * 16 + lr;
        float v = acc[mi][ni][r];
        if (MODE == 0) {
          float bvv = ldsel(bias, n, pf);
          int b = m >> 13;
          if (n < cDI)
            ((unsigned short*)out)[(size_t)m * cDI + n] =
                (unsigned short)f2bf(v + bvv + extra[b * cDI + n]);
          else
            out2[(size_t)m * cDI + (n - cDI)] = (unsigned short)f2bf(v + bvv);
        } else if (MODE == 1) {
          if (n < cK * XROW) {
            int k = n / XROW, c = n - k * XROW;
            int b = m >> 13, vv = m & (cL - 1);
            int t = vv >> 10, q = vv & 1023, h = q >> 5, w = q & 31;
            int l1 = (t << 10) + (w << 5) + h;
            int lk = (k == 0) ? vv : (k == 1) ? l1 : (k == 2) ? (cL - 1 - vv) : (cL - 1 - l1);
            out[((size_t)(b * cK + k) * cL + lk) * XSTR + c] = v;
          }
        } else if (MODE == 2) {
          out[(size_t)m * cC + n] = v + extra[(size_t)m * cC + n];
        } else if (MODE == 3) {
          ((unsigned short*)out)[(size_t)m * cHID + n] =
              (unsigned short)f2bf(gelut(v + ldsel(bias, n, pf)));
        } else {
          out[(size_t)m * cC + n] = v + ldsel(bias, n, pf) + extra[(size_t)m * cC + n];
        }
      }
    }
  }
}

// voxel index for scan position l in direction k
DEV int scan_voxel(int k, int l) {
  if (k == 0) return l;
  if (k == 2) return cL - 1 - l;
  int ll = (k == 1) ? l : (cL - 1 - l);
  int t = ll >> 10, q = ll & 1023, w = q >> 5, h = q & 31;
  return (t << 10) + (h << 5) + w;
}

// ---------- register row structs (constant-indexed, SROA-friendly) ----------
struct Row11 { float4 r0, r1, r2, r3, r4, r5, r6, r7, r8, r9, r10; };
struct Row7  { float4 r0, r1, r2, r7, r8, r9, r10; };

DEV Row11 ldrow11(const float* __restrict__ rows, int st) {
  const float4* rp = (const float4*)(rows + st * XSTR);
  Row11 q;
  q.r0 = rp[0]; q.r1 = rp[1]; q.r2 = rp[2]; q.r3 = rp[3]; q.r4 = rp[4];
  q.r5 = rp[5]; q.r6 = rp[6]; q.r7 = rp[7]; q.r8 = rp[8]; q.r9 = rp[9];
  q.r10 = rp[10];
  return q;
}
DEV Row7 ldrow7(const float* __restrict__ rows, int st) {
  const float4* rp = (const float4*)(rows + st * XSTR);
  Row7 q;
  q.r0 = rp[0]; q.r1 = rp[1]; q.r2 = rp[2];
  q.r7 = rp[7]; q.r8 = rp[8]; q.r9 = rp[9]; q.r10 = rp[10];
  return q;
}

// one fast-path scan1 step: consumes q (row regs) + u, updates h/P1, returns y
DEV float s1step(const Row11& q, float u,
                 const float (&wdt)[cDTR], float dtb, float ac0, float Dsd,
                 float (&h)[cN], float& P1) {
  float s0 = dtb + q.r0.x*wdt[0] + q.r0.z*wdt[2] + q.r1.x*wdt[4] + q.r1.z*wdt[6] + q.r2.x*wdt[8] + q.r2.z*wdt[10];
  float s1 = q.r0.y*wdt[1] + q.r0.w*wdt[3] + q.r1.y*wdt[5] + q.r1.w*wdt[7] + q.r2.y*wdt[9] + q.r2.w*wdt[11];
  float dt = softplusf(s0 + s1);
  float a1 = exp2f(dt * ac0);
  float a2 = a1*a1, a3 = a2*a1, a4 = a2*a2;
  float a5 = a4*a1, a6 = a4*a2, a7 = a4*a3, a8 = a4*a4;
  float a9 = a8*a1, a10 = a8*a2, a11 = a8*a3, a12 = a8*a4;
  float a13 = a8*a5, a14 = a8*a6, a15 = a8*a7, a16 = a8*a8;
  float dtu = dt * u;
  P1 *= a1;
  float yp0 = Dsd * u, yp1 = 0.f, yp2 = 0.f, yp3 = 0.f;
  h[0]  = h[0] *a1  + dtu*q.r3.x; yp0 += h[0] *q.r7.x;
  h[1]  = h[1] *a2  + dtu*q.r3.y; yp1 += h[1] *q.r7.y;
  h[2]  = h[2] *a3  + dtu*q.r3.z; yp2 += h[2] *q.r7.z;
  h[3]  = h[3] *a4  + dtu*q.r3.w; yp3 += h[3] *q.r7.w;
  h[4]  = h[4] *a5  + dtu*q.r4.x; yp0 += h[4] *q.r8.x;
  h[5]  = h[5] *a6  + dtu*q.r4.y; yp1 += h[5] *q.r8.y;
  h[6]  = h[6] *a7  + dtu*q.r4.z; yp2 += h[6] *q.r8.z;
  h[7]  = h[7] *a8  + dtu*q.r4.w; yp3 += h[7] *q.r8.w;
  h[8]  = h[8] *a9  + dtu*q.r5.x; yp0 += h[8] *q.r9.x;
  h[9]  = h[9] *a10 + dtu*q.r5.y; yp1 += h[9] *q.r9.y;
  h[10] = h[10]*a11 + dtu*q.r5.z; yp2 += h[10]*q.r9.z;
  h[11] = h[11]*a12 + dtu*q.r5.w; yp3 += h[11]*q.r9.w;
  h[12] = h[12]*a13 + dtu*q.r6.x; yp0 += h[12]*q.r10.x;
  h[13] = h[13]*a14 + dtu*q.r6.y; yp1 += h[13]*q.r10.y;
  h[14] = h[14]*a15 + dtu*q.r6.z; yp2 += h[14]*q.r10.z;
  h[15] = h[15]*a16 + dtu*q.r6.w; yp3 += h[15]*q.r10.w;
  return (yp0 + yp1) + (yp2 + yp3);
}

// one fast-path scan3 step: evolves g, returns correction y
DEV float s3step(const Row7& q,
                 const float (&wdt)[cDTR], float dtb, float ac0,
                 float (&g)[cN]) {
  float s0 = dtb + q.r0.x*wdt[0] + q.r0.z*wdt[2] + q.r1.x*wdt[4] + q.r1.z*wdt[6] + q.r2.x*wdt[8] + q.r2.z*wdt[10];
  float s1 = q.r0.y*wdt[1] + q.r0.w*wdt[3] + q.r1.y*wdt[5] + q.r1.w*wdt[7] + q.r2.y*wdt[9] + q.r2.w*wdt[11];
  float dt = softplusf(s0 + s1);
  float a1 = exp2f(dt * ac0);
  float a2 = a1*a1, a3 = a2*a1, a4 = a2*a2;
  float a5 = a4*a1, a6 = a4*a2, a7 = a4*a3, a8 = a4*a4;
  float a9 = a8*a1, a10 = a8*a2, a11 = a8*a3, a12 = a8*a4;
  float a13 = a8*a5, a14 = a8*a6, a15 = a8*a7, a16 = a8*a8;
  float yp0 = 0.f, yp1 = 0.f, yp2 = 0.f, yp3 = 0.f;
  g[0]  *= a1;  yp0 += g[0] *q.r7.x;
  g[1]  *= a2;  yp1 += g[1] *q.r7.y;
  g[2]  *= a3;  yp2 += g[2] *q.r7.z;
  g[3]  *= a4;  yp3 += g[3] *q.r7.w;
  g[4]  *= a5;  yp0 += g[4] *q.r8.x;
  g[5]  *= a6;  yp1 += g[5] *q.r8.y;
  g[6]  *= a7;  yp2 += g[6] *q.r8.z;
  g[7]  *= a8;  yp3 += g[7] *q.r8.w;
  g[8]  *= a9;  yp0 += g[8] *q.r9.x;
  g[9]  *= a10; yp1 += g[9] *q.r9.y;
  g[10] *= a11; yp2 += g[10]*q.r9.z;
  g[11] *= a12; yp3 += g[11]*q.r9.w;
  g[12] *= a13; yp0 += g[12]*q.r10.x;
  g[13] *= a14; yp1 += g[13]*q.r10.y;
  g[14] *= a15; yp2 += g[14]*q.r10.z;
  g[15] *= a16; yp3 += g[15]*q.r10.w;
  return (yp0 + yp1) + (yp2 + yp3);
}

// ---------- scan pass 1 (atomic-free: owned l-ordered bf16 streams) ----------
__global__ void __launch_bounds__(128, 3) scan1_kernel(
    const unsigned short* __restrict__ xch, const float* __restrict__ xdbl,
    const void* __restrict__ dtw, const void* __restrict__ dtbv,
    const void* __restrict__ alog, const void* __restrict__ dsv,
    const int* __restrict__ flg,
    unsigned short* __restrict__ ys0, unsigned short* __restrict__ ys1,
    unsigned short* __restrict__ ys2, unsigned short* __restrict__ ys3,
    unsigned short* __restrict__ hend, unsigned short* __restrict__ pend) {
  __shared__ float rows[SEGLEN * XSTR];   // 64 x 48 floats = 12 KB
  int pf = flg[1];
  int tid = threadIdx.x;
  int d = blockIdx.x * 128 + tid;
  int bks = blockIdx.y;
  int s = bks & (SEG - 1); int bk = bks / SEG; int k = bk & 3; int b = bk >> 2;
  int l0 = s * SEGLEN;
  {
    const float4* src = (const float4*)(xdbl + ((size_t)bk * cL + l0) * XSTR);
    float4* dst = (float4*)rows;
#pragma unroll
    for (int i = 0; i < (SEGLEN * XSTR / 4) / 128; ++i)   // 6 iters
      dst[tid + i * 128] = src[tid + i * 128];
  }
  float wdt[cDTR];
#pragma unroll
  for (int r = 0; r < cDTR; ++r) wdt[r] = ldsel(dtw, (size_t)(k * cDI + d) * cDTR + r, pf);
  float dtb = ldsel(dtbv, k * cDI + d, pf);
  float ac[cN];
#pragma unroll
  for (int n = 0; n < cN; ++n)
    ac[n] = -__expf(ldsel(alog, (size_t)(k * cDI + d) * cN + n, pf)) * 1.4426950408889634f;
  bool fast = true;
#pragma unroll
  for (int n = 1; n < cN; ++n)
    fast = fast && (fabsf(ac[n] - (float)(n + 1) * ac[0]) <= 1e-3f * fabsf(ac[n]));
  float Dsd = ldsel(dsv, k * cDI + d, pf);
  float h[cN];
#pragma unroll
  for (int n = 0; n < cN; ++n) h[n] = 0.f;
  size_t so = ((size_t)bks * cDI + d) * cN;
  const unsigned short* xcb = xch + (size_t)b * cL * cDI + d;
  unsigned short* ysk = (k == 0) ? ys0 : (k == 1) ? ys1 : (k == 2) ? ys2 : ys3;
  unsigned short* ysrow = ysk + ((size_t)b * cL + l0) * cDI + d;
  __syncthreads();
  if (fast) {
    float ac0 = ac[0];
    float P1 = 1.f;
    Row11 qa = ldrow11(rows, 0);
    float u0 = bfu2f(xcb[(size_t)scan_voxel(k, l0) * cDI]);
    float u1 = bfu2f(xcb[(size_t)scan_voxel(k, l0 + 1) * cDI]);
    for (int st = 0; st < SEGLEN; st += 2) {
      Row11 qb = ldrow11(rows, st + 1);
      int p2 = (st + 2 < SEGLEN) ? st + 2 : SEGLEN - 1;
      int p3 = (st + 3 < SEGLEN) ? st + 3 : SEGLEN - 1;
      float nu0 = bfu2f(xcb[(size_t)scan_voxel(k, l0 + p2) * cDI]);
      float nu1 = bfu2f(xcb[(size_t)scan_voxel(k, l0 + p3) * cDI]);
      float ya = s1step(qa, u0, wdt, dtb, ac0, Dsd, h, P1);
      ysrow[(size_t)st * cDI] = (unsigned short)f2bf(ya);
      qa = ldrow11(rows, p2);
      float yb = s1step(qb, u1, wdt, dtb, ac0, Dsd, h, P1);
      ysrow[(size_t)(st + 1) * cDI] = (unsigned short)f2bf(yb);
      u0 = nu0; u1 = nu1;
    }
    float pp = P1;
#pragma unroll
    for (int n = 0; n < cN; ++n) {
      hend[so + n] = (unsigned short)f2bf(h[n]);
      pend[so + n] = (unsigned short)f2bf(pp);
      pp *= P1;
    }
  } else {
    float P[cN];
#pragma unroll
    for (int n = 0; n < cN; ++n) P[n] = 1.f;
    for (int st = 0; st < SEGLEN; ++st) {
      int l = l0 + st;
      const float4* rp = (const float4*)(rows + st * XSTR);
      float4 q0 = rp[0], q1 = rp[1], q2 = rp[2];
      float s0 = dtb + q0.x*wdt[0] + q0.z*wdt[2] + q1.x*wdt[4] + q1.z*wdt[6] + q2.x*wdt[8] + q2.z*wdt[10];
      float s1 = q0.y*wdt[1] + q0.w*wdt[3] + q1.y*wdt[5] + q1.w*wdt[7] + q2.y*wdt[9] + q2.w*wdt[11];
      float dt = softplusf(s0 + s1);
      float Bv[cN], Cv[cN];
      float4 qb0 = rp[3], qb1 = rp[4], qb2 = rp[5], qb3 = rp[6];
      float4 qc0 = rp[7], qc1 = rp[8], qc2 = rp[9], qc3 = rp[10];
      Bv[0]=qb0.x; Bv[1]=qb0.y; Bv[2]=qb0.z; Bv[3]=qb0.w;
      Bv[4]=qb1.x; Bv[5]=qb1.y; Bv[6]=qb1.z; Bv[7]=qb1.w;
      Bv[8]=qb2.x; Bv[9]=qb2.y; Bv[10]=qb2.z; Bv[11]=qb2.w;
      Bv[12]=qb3.x; Bv[13]=qb3.y; Bv[14]=qb3.z; Bv[15]=qb3.w;
      Cv[0]=qc0.x; Cv[1]=qc0.y; Cv[2]=qc0.z; Cv[3]=qc0.w;
      Cv[4]=qc1.x; Cv[5]=qc1.y; Cv[6]=qc1.z; Cv[7]=qc1.w;
      Cv[8]=qc2.x; Cv[9]=qc2.y; Cv[10]=qc2.z; Cv[11]=qc2.w;
      Cv[12]=qc3.x; Cv[13]=qc3.y; Cv[14]=qc3.z; Cv[15]=qc3.w;
      int v = scan_voxel(k, l);
      float u = bfu2f(xcb[(size_t)v * cDI]);
      float dtu = dt * u;
      float y = Dsd * u;
#pragma unroll
      for (int n = 0; n < cN; ++n) {
        float a = exp2f(dt * ac[n]);
        h[n] = h[n] * a + dtu * Bv[n];
        P[n] *= a;
        y += h[n] * Cv[n];
      }
      ysrow[(size_t)st * cDI] = (unsigned short)f2bf(y);
    }
#pragma unroll
    for (int n = 0; n < cN; ++n) {
      hend[so + n] = (unsigned short)f2bf(h[n]);
      pend[so + n] = (unsigned short)f2bf(P[n]);
    }
  }
}

// ---------- scan pass 2 (serial prefix over segments; fp32 recurrence, bf16 storage) ----------
__global__ void __launch_bounds__(256) scan2_kernel(
    unsigned short* __restrict__ hend, const unsigned short* __restrict__ pend) {
  int tid = blockIdx.x * 256 + threadIdx.x;
  int bk = tid / (cDI * cN); int r = tid - bk * (cDI * cN);
  float g = 0.f;
  for (int s = 0; s < SEG; ++s) {
    size_t o = ((size_t)(bk * SEG + s) * cDI * cN) + r;
    float he = bfu2f(hend[o]), pe = bfu2f(pend[o]);
    hend[o] = (unsigned short)f2bf(g);
    g = pe * g + he;
  }
}

// ---------- scan pass 3 (owned read-add-store on l-ordered rows; no atomics) ----------
__global__ void __launch_bounds__(128, 3) scan3_kernel(
    const float* __restrict__ xdbl,
    const void* __restrict__ dtw, const void* __restrict__ dtbv,
    const void* __restrict__ alog, const int* __restrict__ flg,
    const unsigned short* __restrict__ hin,
    unsigned short* __restrict__ ys0, unsigned short* __restrict__ ys1,
    unsigned short* __restrict__ ys2, unsigned short* __restrict__ ys3) {
  int bks = blockIdx.y;
  int s = bks & (SEG - 1);
  if (s == 0) return;
  __shared__ float rows[SEGLEN * XSTR];
  int pf = flg[1];
  int tid = threadIdx.x;
  int d = blockIdx.x * 128 + tid;
  int bk = bks / SEG; int k = bk & 3; int b = bk >> 2;
  int l0 = s * SEGLEN;
  {
    const float4* src = (const float4*)(xdbl + ((size_t)bk * cL + l0) * XSTR);
    float4* dst = (float4*)rows;
#pragma unroll
    for (int i = 0; i < (SEGLEN * XSTR / 4) / 128; ++i)
      dst[tid + i * 128] = src[tid + i * 128];
  }
  float wdt[cDTR];
#pragma unroll
  for (int r = 0; r < cDTR; ++r) wdt[r] = ldsel(dtw, (size_t)(k * cDI + d) * cDTR + r, pf);
  float dtb = ldsel(dtbv, k * cDI + d, pf);
  float ac[cN];
#pragma unroll
  for (int n = 0; n < cN; ++n)
    ac[n] = -__expf(ldsel(alog, (size_t)(k * cDI + d) * cN + n, pf)) * 1.4426950408889634f;
  bool fast = true;
#pragma unroll
  for (int n = 1; n < cN; ++n)
    fast = fast && (fabsf(ac[n] - (float)(n + 1) * ac[0]) <= 1e-3f * fabsf(ac[n]));
  float g[cN];
  size_t so = ((size_t)bks * cDI + d) * cN;
#pragma unroll
  for (int n = 0; n < cN; ++n) g[n] = bfu2f(hin[so + n]);
  unsigned short* ysk = (k == 0) ? ys0 : (k == 1) ? ys1 : (k == 2) ? ys2 : ys3;
  unsigned short* ysrow = ysk + ((size_t)b * cL + l0) * cDI + d;
  __syncthreads();
  if (fast) {
    float ac0 = ac[0];
    Row7 qa = ldrow7(rows, 0);
    for (int st = 0; st < SEGLEN; st += 2) {
      Row7 qb = ldrow7(rows, st + 1);
      int p2 = (st + 2 < SEGLEN) ? st + 2 : SEGLEN - 1;
      float ya = s3step(qa, wdt, dtb, ac0, g);
      size_t ia = (size_t)st * cDI;
      ysrow[ia] = (unsigned short)f2bf(bfu2f(ysrow[ia]) + ya);
      qa = ldrow7(rows, p2);
      float yb = s3step(qb, wdt, dtb, ac0, g);
      size_t ib = (size_t)(st + 1) * cDI;
      ysrow[ib] = (unsigned short)f2bf(bfu2f(ysrow[ib]) + yb);
    }
  } else {
    for (int st = 0; st < SEGLEN; ++st) {
      const float4* rp = (const float4*)(rows + st * XSTR);
      float4 q0 = rp[0], q1 = rp[1], q2 = rp[2];
      float s0 = dtb + q0.x*wdt[0] + q0.z*wdt[2] + q1.x*wdt[4] + q1.z*wdt[6] + q2.x*wdt[8] + q2.z*wdt[10];
      float s1 = q0.y*wdt[1] + q0.w*wdt[3] + q1.y*wdt[5] + q1.w*wdt[7] + q2.y*wdt[9] + q2.w*wdt[11];
      float dt = softplusf(s0 + s1);
      float Cv[cN];
      float4 qc0 = rp[7], qc1 = rp[8], qc2 = rp[9], qc3 = rp[10];
      Cv[0]=qc0.x; Cv[1]=qc0.y; Cv[2]=qc0.z; Cv[3]=qc0.w;
      Cv[4]=qc1.x; Cv[5]=qc1.y; Cv[6]=qc1.z; Cv[7]=qc1.w;
      Cv[8]=qc2.x; Cv[9]=qc2.y; Cv[10]=qc2.z; Cv[11]=qc2.w;
      Cv[12]=qc3.x; Cv[13]=qc3.y; Cv[14]=qc3.z; Cv[15]=qc3.w;
      float y = 0.f;
#pragma unroll
      for (int n = 0; n < cN; ++n) {
        float a = exp2f(dt * ac[n]);
        g[n] *= a;
        y += g[n] * Cv[n];
      }
      size_t ii = (size_t)st * cDI;
      ysrow[ii] = (unsigned short)f2bf(bfu2f(ysrow[ii]) + y);
    }
  }
}

// ---------- merge: gather 4 directions + out_norm LN + silu(z) gate ----------
__global__ void __launch_bounds__(128) merge_kernel(
    const unsigned short* __restrict__ ys0, const unsigned short* __restrict__ ys1,
    const unsigned short* __restrict__ ys2, const unsigned short* __restrict__ ys3,
    const unsigned short* __restrict__ zh,
    const void* __restrict__ ong, const void* __restrict__ onb,
    const int* __restrict__ flg, unsigned short* __restrict__ yg) {
  int pf = flg[1];
  int bv = blockIdx.x;
  int v = bv & (cL - 1); int b = bv >> 13;
  int t = v >> 10, q = v & 1023, hh = q >> 5, ww = q & 31;
  int l1 = (t << 10) + (ww << 5) + hh;
  size_t r0 = ((size_t)b * cL + v) * cDI;
  size_t r1 = ((size_t)b * cL + l1) * cDI;
  size_t r2 = ((size_t)b * cL + (cL - 1 - v)) * cDI;
  size_t r3 = ((size_t)b * cL + (cL - 1 - l1)) * cDI;
  float vals[3]; float s1 = 0.f, s2 = 0.f;
#pragma unroll
  for (int i = 0; i < 3; ++i) {
    int d = threadIdx.x + i * 128;
    float x = bfu2f(ys0[r0 + d]) + bfu2f(ys1[r1 + d]) +
              bfu2f(ys2[r2 + d]) + bfu2f(ys3[r3 + d]);
    vals[i] = x; s1 += x; s2 += x * x;
  }
  blkreduce2<128>(s1, s2);
  float mean = s1 * (1.f / cDI);
  float var = s2 * (1.f / cDI) - mean * mean;
  float rstd = rsqrtf(var + 1e-6f);
  const unsigned short* zr = zh + (size_t)bv * cDI;
  unsigned short* og = yg + (size_t)bv * cDI;
#pragma unroll
  for (int i = 0; i < 3; ++i) {
    int d = threadIdx.x + i * 128;
    float xn = (vals[i] - mean) * rstd * ldsel(ong, d, pf) + ldsel(onb, d, pf);
    og[d] = (unsigned short)f2bf(xn * siluf(bfu2f(zr[d])));
  }
}

}  // namespace

extern "C" void kernel_launch(void* const* d_in, const int* in_sizes, int n_in,
                              void* d_out, int out_size, void* d_ws, size_t ws_size,
                              hipStream_t stream) {
  (void)in_sizes; (void)n_in; (void)out_size; (void)ws_size;
  const void* x    = d_in[0];
  const void* text = d_in[1];
  const void* c1w  = d_in[2];
  const void* c1b  = d_in[3];
  const void* c2w  = d_in[4];
  const void* c2b  = d_in[5];
  const void* n1g  = d_in[6];
  const void* n1b  = d_in[7];
  const void* n2g  = d_in[8];
  const void* n2b  = d_in[9];
  const void* ipw  = d_in[10];
  const void* ipb  = d_in[11];
  const void* tpw  = d_in[12];
  const void* tpb  = d_in[13];
  const void* cvw  = d_in[14];
  const void* cvb  = d_in[15];
  const void* xpw  = d_in[16];
  const void* dtw  = d_in[17];
  const void* dtb  = d_in[18];
  const void* alog = d_in[19];
  const void* dsv  = d_in[20];
  const void* ong  = d_in[21];
  const void* onb  = d_in[22];
  const void* opw  = d_in[23];
  const void* f1w  = d_in[24];
  const void* f1b  = d_in[25];
  const void* f2w  = d_in[26];
  const void* f2b  = d_in[27];

  float* Wf = (float*)d_ws;

  // ---- slot arena (~125.9 MB), atomic-free scan + bf16 activations ----
  constexpr size_t oC  = 0;                              // 6,291,456
  constexpr size_t oD  = 6291456;                        // 3,145,728
  constexpr size_t oG  = 9437184;                        // 3,145,728
  constexpr size_t oA  = 12582912;                       // 6,291,456
  constexpr size_t oB  = 18874368;                       // 6,291,456
  constexpr size_t oE  = 25165824;                       // 3,145,728
  constexpr size_t oF  = 28311552;                       // 3,145,728
  constexpr size_t oCO = 31457280;                       // 768 (cond)
  constexpr size_t oFL = 31458048;                       // 4 ints (flags)
  constexpr size_t oWCV = 31458052;                      // 27*384
  constexpr size_t oBCV = 31468420;                      // 384
  constexpr size_t oW1  = 31468804;                      // 27*192
  constexpr size_t oB1  = 31473988;                      // 192
  constexpr size_t oW2  = 31474180;                      // 5184
  constexpr size_t oB2  = 31479364;                      // 192 -> end 31479556
  unsigned short* xch = (unsigned short*)(Wf + oC);            // bf16 silu(dwconv)
  unsigned short* ysd2 = (unsigned short*)(Wf + oC + 3145728); // ystream dir 2
  unsigned short* hbufh = (unsigned short*)(Wf + oC);          // fc1 out bf16 (25.2MB = oC)
  float* xdbl = Wf + oD;
  unsigned short* ygh  = (unsigned short*)(Wf + oD);           // yg bf16 (after xdbl dead)
  unsigned short* xnh  = (unsigned short*)(Wf + oG);           // LN1 out bf16
  unsigned short* pendp = (unsigned short*)(Wf + oG);          // bf16, after xnh dead
  unsigned short* xib  = (unsigned short*)(Wf + oA);           // in_proj x-half bf16
  unsigned short* ysd0 = (unsigned short*)(Wf + oA);           // ystream dir 0 (xib dead)
  unsigned short* ysd1 = (unsigned short*)(Wf + oA + 3145728); // ystream dir 1
  float* x2   = Wf + oA;   // out_proj output (after ystream dead)
  unsigned short* zh   = (unsigned short*)(Wf + oB);           // z bf16
  unsigned short* ysd3 = (unsigned short*)(Wf + oB + 3145728); // ystream dir 3
  float* x3   = Wf + oB;
  float* x1   = Wf + oE;
  unsigned short* hendp = (unsigned short*)(Wf + oF);          // bf16
  unsigned short* xn2h = (unsigned short*)(Wf + oF);           // LN2 out bf16 (hend dead)
  float* cond = Wf + oCO;
  int*   flg  = (int*)(Wf + oFL);
  float* wcv = Wf + oWCV; float* bcv = Wf + oBCV;
  float* w1t = Wf + oW1;  float* b1t = Wf + oB1;
  float* w2t = Wf + oW2;  float* b2t = Wf + oB2;

  const int cpeBlocks = (cBL * cC / 4) / 256;     // 3072
  const int dwBlocks  = (cBL * cDI / 4) / 256;    // 6144

  // 0. dtype detection + conv weight prep
  hipLaunchKernelGGL(detect_kernel, dim3(1), dim3(256), 0, stream,
                     (const unsigned short*)x, (const unsigned short*)ipw, flg);
  hipLaunchKernelGGL(prep_kernel, dim3(85), dim3(256), 0, stream,
                     cvw, cvb, c1w, c1b, c2w, c2b, flg, wcv, bcv, w1t, b1t, w2t, b2t);
  // 1. x1 = x + cpe1(x)
  hipLaunchKernelGGL(cpe_kernel, dim3(cpeBlocks), dim3(256), 0, stream,
                     x, w1t, b1t, flg, 0, x1);
  // 2. xnh = bf16(LN1(x1))  (wave-per-row, no barriers)
  hipLaunchKernelGGL(lnb_kernel, dim3(cBL / 4), dim3(256), 0, stream, x1, n1g, n1b, flg, xnh);
  // 3. cond
  hipLaunchKernelGGL(text_cond_kernel, dim3(cB), dim3(384), 0, stream, text, tpw, tpb, flg, cond);
  // 4. in_proj (MFMA, bf16 A): xnh -> xib bf16 (+cond), zh bf16
  hipLaunchKernelGGL((gemm_mfma_kernel<0, 1>), dim3(2 * cDI / 64, cBL / 128), dim3(256), 0, stream,
                     xnh, ipw, 2 * cDI, cC, ipb, flg, cond, (float*)xib, zh);
  // 5. xch = bf16(silu(dwconv(xib)))
  hipLaunchKernelGGL(dwconv_silu_kernel, dim3(dwBlocks), dim3(256), 0, stream,
                     xib, wcv, bcv, xch);
  // 6. x_proj (MFMA, bf16 A, scatter to padded scan rows)
  hipLaunchKernelGGL((gemm_mfma_kernel<1, 1>), dim3((cK * XROW + 63) / 64, cBL / 128), dim3(256), 0, stream,
                     xch, xpw, cK * XROW, cDI, (const void*)nullptr, flg,
                     (const float*)nullptr, xdbl, (unsigned short*)nullptr);
  // 7-9. chunked selective scan (atomic-free: plain bf16 streaming stores)
  hipLaunchKernelGGL(scan1_kernel, dim3(cDI / 128, cB * cK * SEG), dim3(128), 0, stream,
                     xch, xdbl, dtw, dtb, alog, dsv, flg,
                     ysd0, ysd1, ysd2, ysd3, hendp, pendp);
  hipLaunchKernelGGL(scan2_kernel, dim3(cB * cK * cDI * cN / 256), dim3(256), 0, stream,
                     hendp, pendp);
  hipLaunchKernelGGL(scan3_kernel, dim3(cDI / 128, cB * cK * SEG), dim3(128), 0, stream,
                     xdbl, dtw, dtb, alog, flg, hendp, ysd0, ysd1, ysd2, ysd3);
  // 10. merge: gather 4 dirs + out_norm + gate -> yg bf16
  hipLaunchKernelGGL(merge_kernel, dim3(cBL), dim3(128), 0, stream,
                     ysd0, ysd1, ysd2, ysd3, zh, ong, onb, flg, ygh);
  // 11. out_proj (bf16 A) + residual(x1) -> x2 fp32
  hipLaunchKernelGGL((gemm_mfma_kernel<2, 1>), dim3(cC / 64, cBL / 128), dim3(256), 0, stream,
                     ygh, opw, cC, cDI, (const void*)nullptr, flg, x1, x2,
                     (unsigned short*)nullptr);
  // 12. x3 = x2 + cpe2(x2)  (flg[2]=1 -> fp32 input path)
  hipLaunchKernelGGL(cpe_kernel, dim3(cpeBlocks), dim3(256), 0, stream,
                     x2, w2t, b2t, flg, 2, x3);
  // 13. xn2h = bf16(LN2(x3))
  hipLaunchKernelGGL(lnb_kernel, dim3(cBL / 4), dim3(256), 0, stream, x3, n2g, n2b, flg, xn2h);
  // 14. fc1 + gelu -> hbufh bf16 (MFMA, bf16 A)
  hipLaunchKernelGGL((gemm_mfma_kernel<3, 1>), dim3(cHID / 64, cBL / 128), dim3(256), 0, stream,
                     xn2h, f1w, cHID, cC, f1b, flg, (const float*)nullptr, (float*)hbufh,
                     (unsigned short*)nullptr);
  // 15. fc2 (bf16 A) + bias + residual(x3) -> d_out fp32 (MFMA)
  hipLaunchKernelGGL((gemm_mfma_kernel<4, 1>), dim3(cC / 64, cBL / 128), dim3(256), 0, stream,
                     hbufh, f2w, cC, cHID, f2b, flg, x3, (float*)d_out,
                     (unsigned short*)nullptr);
}